// Round 3
// baseline (2885.056 us; speedup 1.0000x reference)
//
#include <hip/hip_runtime.h>
#include <float.h>
#include <math.h>

#define NTOK 16384
#define KCB  2048
#define DDIM 256
#define NCB  10

// ---- np-bit-exact pairwise sum of squares for rows of length 256 ----
// numpy pairwise_sum(n=256): split 128+128; each half: r[j] = sq[j]; r[j] += sq[8k+j]
// (k=1..15 ascending); half = ((r0+r1)+(r2+r3))+((r4+r5)+(r6+r7)); total = lo + hi.
// Squares are rounded separately (temp = flat*flat), adds are plain f32 adds -> use
// __fmul_rn/__fadd_rn to block -ffp-contract=fast fusion.
// Mapping: 4 rows/wave, 16 lanes/row: lane l: half=l>>3, j=l&7; xor-butterfly 1,2,4,8
// reproduces np's association exactly (f32 add is commutative).
__global__ __launch_bounds__(256) void norms_np_kernel(const float* __restrict__ src,
                                                       float* __restrict__ dst,
                                                       int nrows) {
    const int gw   = (blockIdx.x * 256 + threadIdx.x) >> 6;
    const int lane = threadIdx.x & 63;
    const int row  = gw * 4 + (lane >> 4);
    const int l    = lane & 15;
    float r = 0.f;
    if (row < nrows) {
        const float* a = src + (size_t)row * DDIM + ((l >> 3) << 7) + (l & 7);
        float v = a[0];
        r = __fmul_rn(v, v);
        #pragma unroll
        for (int k = 1; k < 16; ++k) {
            v = a[k * 8];
            r = __fadd_rn(r, __fmul_rn(v, v));
        }
    }
    r = __fadd_rn(r, __shfl_xor(r, 1, 64));
    r = __fadd_rn(r, __shfl_xor(r, 2, 64));
    r = __fadd_rn(r, __shfl_xor(r, 4, 64));
    r = __fadd_rn(r, __shfl_xor(r, 8, 64));
    if (row < nrows && l == 0) dst[row] = r;
}

// ---- distance GEMM + per-slice argmin (bitwise-replicating np's quantized dist) ----
// np: dist = fl(fl(A - X2) + C), X2 = (2*flat) @ Ei.T (sequential ascending-k FMA chain
// in BLAS microkernel). Scaling by 2 commutes with rounding, so X2 == 2*acc bitwise and
// fmaf(-2,acc,A) == fl(A - X2). Ties -> lowest index (np.argmin first-min).
__global__ __launch_bounds__(256) void vq_main(const float* __restrict__ resSrc,
                                               const float* __restrict__ Ei,
                                               const float* __restrict__ sseEi,
                                               const float* __restrict__ normA,
                                               float* __restrict__ pm1,
                                               int* __restrict__ pi1) {
    __shared__ float sRes[128 * 36];   // stride 36: b128 lane stride -> 2-way (free)
    __shared__ float sE[64 * 36];
    __shared__ float sA[128];
    const int tid = threadIdx.x;
    const int tx = tid & 15, ty = tid >> 4;
    const int slice = blockIdx.x & 31;
    const int tile  = blockIdx.x >> 5;
    const int t0 = tile * 128;
    const int kc = slice * 64;

    if (tid < 128) sA[tid] = normA[t0 + tid];

    float acc[8][4];
    #pragma unroll
    for (int i = 0; i < 8; ++i)
        #pragma unroll
        for (int j = 0; j < 4; ++j) acc[i][j] = 0.f;

    for (int dc = 0; dc < 8; ++dc) {
        const int db = dc * 32;
        __syncthreads();
        #pragma unroll
        for (int p = 0; p < 4; ++p) {               // stage 128x32 residual chunk
            int chunk = tid + p * 256;
            int tt = chunk >> 3, dq = chunk & 7;
            *(float4*)(&sRes[tt * 36 + dq * 4]) =
                *(const float4*)(resSrc + (size_t)(t0 + tt) * DDIM + db + dq * 4);
        }
        #pragma unroll
        for (int p = 0; p < 2; ++p) {               // stage 64x32 E chunk
            int chunk = tid + p * 256;
            int cc = chunk >> 3, dq = chunk & 7;
            *(float4*)(&sE[cc * 36 + dq * 4]) =
                *(const float4*)(Ei + (size_t)(kc + cc) * DDIM + db + dq * 4);
        }
        __syncthreads();
        #pragma unroll
        for (int dq = 0; dq < 8; ++dq) {            // k ascending: dc, dq, x,y,z,w
            float4 b[4];
            #pragma unroll
            for (int j = 0; j < 4; ++j)
                b[j] = *(const float4*)(&sE[(tx + 16 * j) * 36 + dq * 4]);
            #pragma unroll
            for (int i = 0; i < 8; ++i) {
                const float4 a = *(const float4*)(&sRes[(ty + 16 * i) * 36 + dq * 4]);
                #pragma unroll
                for (int j = 0; j < 4; ++j) {
                    acc[i][j] = fmaf(a.x, b[j].x, acc[i][j]);
                    acc[i][j] = fmaf(a.y, b[j].y, acc[i][j]);
                    acc[i][j] = fmaf(a.z, b[j].z, acc[i][j]);
                    acc[i][j] = fmaf(a.w, b[j].w, acc[i][j]);
                }
            }
        }
    }

    // per-thread argmin over its 4 codes (c ascending within thread: first-min wins)
    float Cf[4];
    #pragma unroll
    for (int j = 0; j < 4; ++j) Cf[j] = sseEi[kc + tx + 16 * j];
    float m1[8]; int i1[8];
    #pragma unroll
    for (int i = 0; i < 8; ++i) { m1[i] = FLT_MAX; i1[i] = 0x7fffffff; }
    #pragma unroll
    for (int i = 0; i < 8; ++i) {
        const float A = sA[ty + 16 * i];
        #pragma unroll
        for (int j = 0; j < 4; ++j) {
            float d1 = fmaf(-2.f, acc[i][j], A);     // == fl(A - X2), X2 = 2*acc exact
            float s  = __fadd_rn(d1, Cf[j]);         // fl(d1 + C): quantized dist
            int c = kc + tx + 16 * j;
            if (s < m1[i]) { m1[i] = s; i1[i] = c; }
        }
    }

    // cross-tx merge (alias tiles; stride 17 -> conflict-free); ties -> lowest index
    float* sM1 = sRes;
    int*   sI1 = (int*)sE;
    __syncthreads();
    #pragma unroll
    for (int i = 0; i < 8; ++i) {
        int t = ty + 16 * i;
        sM1[t * 17 + tx] = m1[i];
        sI1[t * 17 + tx] = i1[i];
    }
    __syncthreads();
    if (tid < 128) {
        int t = tid;
        float gm1 = FLT_MAX; int gi1 = 0x7fffffff;
        for (int x = 0; x < 16; ++x) {
            float v1 = sM1[t * 17 + x];
            int ii = sI1[t * 17 + x];
            if (v1 < gm1 || (v1 == gm1 && ii < gi1)) { gm1 = v1; gi1 = ii; }
        }
        size_t o = (size_t)(t0 + t) * 32 + slice;
        pm1[o] = gm1; pi1[o] = gi1;
    }
}

// ---- merge slices; elementwise-exact f32 chain update (pure adds: contraction-safe) --
__global__ __launch_bounds__(256) void vq_finalize(const float* __restrict__ z,
                                                   const float* __restrict__ Ei,
                                                   float* __restrict__ res,
                                                   float* __restrict__ zq,
                                                   float* __restrict__ codes,
                                                   float* __restrict__ vql,
                                                   const float* __restrict__ pm1,
                                                   const int* __restrict__ pi1,
                                                   int iter) {
    __shared__ int sIdx[64];
    __shared__ float sRed[4];
    const int tid = threadIdx.x;
    const int t0 = blockIdx.x * 64;

    if (tid < 64) {
        float m1 = FLT_MAX; int i1 = 0x7fffffff;
        size_t base = (size_t)(t0 + tid) * 32;
        for (int s = 0; s < 32; ++s) {
            float v = pm1[base + s]; int ii = pi1[base + s];
            if (v < m1 || (v == m1 && ii < i1)) { m1 = v; i1 = ii; }
        }
        sIdx[tid] = i1;
        codes[(size_t)(t0 + tid) * NCB + iter] = (float)i1;
    }
    __syncthreads();

    const int w = tid >> 6, l = tid & 63;
    float lsum = 0.f;
    for (int s = 0; s < 16; ++s) {
        const int tt = w * 16 + s;
        const int t = t0 + tt;
        const size_t go = (size_t)t * DDIM + l * 4;
        const int idx = sIdx[tt];
        const float4 r4 = (iter == 0) ? *(const float4*)(z + go) : *(const float4*)(res + go);
        const float4 q4 = *(const float4*)(Ei + (size_t)idx * DDIM + l * 4);
        float4 rn4, zqi4;
        // reference elementwise f32: t = fl(q-r); z_q = fl(r+t); r' = fl(r-z_q)
        float tqx = q4.x - r4.x; zqi4.x = r4.x + tqx; rn4.x = r4.x - zqi4.x;
        float tqy = q4.y - r4.y; zqi4.y = r4.y + tqy; rn4.y = r4.y - zqi4.y;
        float tqz = q4.z - r4.z; zqi4.z = r4.z + tqz; rn4.z = r4.z - zqi4.z;
        float tqw = q4.w - r4.w; zqi4.w = r4.w + tqw; rn4.w = r4.w - zqi4.w;
        lsum = fmaf(tqx, tqx, lsum); lsum = fmaf(tqy, tqy, lsum);
        lsum = fmaf(tqz, tqz, lsum); lsum = fmaf(tqw, tqw, lsum);
        *(float4*)(res + go) = rn4;
        if (iter == 0) {
            *(float4*)(zq + go) = zqi4;
        } else {
            float4 o4 = *(float4*)(zq + go);
            o4.x += zqi4.x; o4.y += zqi4.y; o4.z += zqi4.z; o4.w += zqi4.w;
            *(float4*)(zq + go) = o4;
        }
    }

    #pragma unroll
    for (int o = 32; o >= 1; o >>= 1) lsum += __shfl_xor(lsum, o, 64);
    if (l == 0) sRed[w] = lsum;
    __syncthreads();
    if (tid == 0)
        atomicAdd(vql, (sRed[0] + sRed[1] + sRed[2] + sRed[3]) * (1.25f / 4194304.f));
}

// ---- semantic head on z_q of codebook 0 ----
__global__ __launch_bounds__(256) void semantic_kernel(const float* __restrict__ zq,
                                                       const float* __restrict__ tgt,
                                                       const float* __restrict__ W1,
                                                       const float* __restrict__ b1,
                                                       const float* __restrict__ W2,
                                                       const float* __restrict__ b2,
                                                       float* __restrict__ semLoss) {
    __shared__ float sQ[16 * 256];
    __shared__ float sH[16 * 256];
    __shared__ float sRed[4];
    const int tid = threadIdx.x;
    const int tb = blockIdx.x * 16;
    #pragma unroll
    for (int tt = 0; tt < 16; ++tt)
        sQ[tt * 256 + tid] = zq[(size_t)(tb + tt) * 256 + tid];
    __syncthreads();
    float hacc[16];
    float bj = b1[tid];
    #pragma unroll
    for (int tt = 0; tt < 16; ++tt) hacc[tt] = bj;
    for (int d = 0; d < 256; ++d) {
        float wv = W1[d * 256 + tid];
        #pragma unroll
        for (int tt = 0; tt < 16; ++tt) hacc[tt] = fmaf(sQ[tt * 256 + d], wv, hacc[tt]);
    }
    #pragma unroll
    for (int tt = 0; tt < 16; ++tt) {
        float x = hacc[tt];
        sH[tt * 256 + tid] = 0.5f * x * (1.0f + erff(x * 0.70710678118654752f));
    }
    __syncthreads();
    float lsum = 0.f;
    for (int mm = 0; mm < 4; ++mm) {
        int m = mm * 256 + tid;
        float pacc[16];
        float bm = b2[m];
        #pragma unroll
        for (int tt = 0; tt < 16; ++tt) pacc[tt] = bm;
        for (int s = 0; s < 256; ++s) {
            float wv = W2[s * 1024 + m];
            #pragma unroll
            for (int tt = 0; tt < 16; ++tt) pacc[tt] = fmaf(sH[tt * 256 + s], wv, pacc[tt]);
        }
        #pragma unroll
        for (int tt = 0; tt < 16; ++tt) {
            float dv = pacc[tt] - tgt[(size_t)(tb + tt) * 1024 + m];
            lsum = fmaf(dv, dv, lsum);
        }
    }
    #pragma unroll
    for (int o = 32; o >= 1; o >>= 1) lsum += __shfl_xor(lsum, o, 64);
    if ((tid & 63) == 0) sRed[tid >> 6] = lsum;
    __syncthreads();
    if (tid == 0) atomicAdd(semLoss, (sRed[0] + sRed[1] + sRed[2] + sRed[3]) * (1.0f / 16777216.f));
}

extern "C" void kernel_launch(void* const* d_in, const int* in_sizes, int n_in,
                              void* d_out, int out_size, void* d_ws, size_t ws_size,
                              hipStream_t stream) {
    const float* z   = (const float*)d_in[0];
    const float* tgt = (const float*)d_in[1];
    const float* E   = (const float*)d_in[2];
    const float* W1  = (const float*)d_in[3];
    const float* b1  = (const float*)d_in[4];
    const float* W2  = (const float*)d_in[5];
    const float* b2  = (const float*)d_in[6];

    float* out   = (float*)d_out;
    float* zq    = out;                                          // 16384*256
    float* codes = out + (size_t)NTOK * DDIM;                    // 16384*10
    float* vql   = codes + (size_t)NTOK * NCB;                   // [vq_loss, semantic_loss]

    char* w = (char*)d_ws;
    float* res   = (float*)w;                                    // 16 MiB
    float* sseE  = (float*)(w + (16u << 20));                    // 80 KiB
    float* normA = (float*)(w + (16u << 20) + (128u << 10));     // 64 KiB
    float* pm1   = (float*)(w + (16u << 20) + (256u << 10));     // 2 MiB
    int*   pi1   = (int*)  (w + (18u << 20) + (256u << 10));     // 2 MiB

    hipMemsetAsync(vql, 0, 2 * sizeof(float), stream);
    norms_np_kernel<<<1280, 256, 0, stream>>>(E, sseE, NCB * KCB);
    norms_np_kernel<<<1024, 256, 0, stream>>>(z, normA, NTOK);
    for (int it = 0; it < NCB; ++it) {
        const float* Ei    = E + (size_t)it * KCB * DDIM;
        const float* sseEi = sseE + (size_t)it * KCB;
        const float* resSrc = (it == 0) ? z : res;
        vq_main<<<4096, 256, 0, stream>>>(resSrc, Ei, sseEi, normA, pm1, pi1);
        vq_finalize<<<256, 256, 0, stream>>>(z, Ei, res, zq, codes, vql, pm1, pi1, it);
        if (it == 0)
            semantic_kernel<<<1024, 256, 0, stream>>>(zq, tgt, W1, b1, W2, b2, vql + 1);
        if (it < NCB - 1)
            norms_np_kernel<<<1024, 256, 0, stream>>>(res, normA, NTOK);
    }
}

// Round 4
// 2676.316 us; speedup vs baseline: 1.0780x; 1.0780x over previous
//
#include <hip/hip_runtime.h>
#include <float.h>
#include <math.h>

#define NTOK 16384
#define KCB  2048
#define DDIM 256
#define NCB  10

typedef __attribute__((ext_vector_type(8))) short  short8;
typedef __attribute__((ext_vector_type(4))) float  f32x4;

static __device__ __forceinline__ unsigned short f2bf(float f) {
    unsigned int b = __float_as_uint(f);
    unsigned int r = b + 0x7FFFu + ((b >> 16) & 1u);   // RNE
    return (unsigned short)(r >> 16);
}

// ---- np-bit-exact pairwise sum of squares (rows of 256): E rows + z rows, one launch --
// lane l of 16 per row: half=l>>3, j=l&7; r = sum_{k=0..15 asc} fl(v*v), v=src[half*128+8k+j];
// then fadd butterfly xor 1,2,4,8 == np's ((r0+r1)+(r2+r3))+((r4+r5)+(r6+r7)), lo+hi.
__global__ __launch_bounds__(256) void norms_all_kernel(const float* __restrict__ E,
                                                        const float* __restrict__ z,
                                                        float* __restrict__ sseE,
                                                        float* __restrict__ normA) {
    const int gw   = (blockIdx.x * 256 + threadIdx.x) >> 6;
    const int lane = threadIdx.x & 63;
    const int row  = gw * 4 + (lane >> 4);
    const int l    = lane & 15;
    const float* src = nullptr; float* dst = nullptr;
    if (row < NCB * KCB)             { src = E + (size_t)row * DDIM;               dst = sseE + row; }
    else if (row < NCB * KCB + NTOK) { src = z + (size_t)(row - NCB * KCB) * DDIM; dst = normA + (row - NCB * KCB); }
    float r = 0.f;
    if (src) {
        const float* a = src + ((l >> 3) << 7) + (l & 7);
        float v = a[0];
        r = __fmul_rn(v, v);
        #pragma unroll
        for (int k = 1; k < 16; ++k) { v = a[k * 8]; r = __fadd_rn(r, __fmul_rn(v, v)); }
    }
    r = __fadd_rn(r, __shfl_xor(r, 1, 64));
    r = __fadd_rn(r, __shfl_xor(r, 2, 64));
    r = __fadd_rn(r, __shfl_xor(r, 4, 64));
    r = __fadd_rn(r, __shfl_xor(r, 8, 64));
    if (src && l == 0) *dst = r;
}

// ---- transpose+convert W1 -> W1T bf16 [256][256], W2 -> W2T bf16 [1024][256] ----
__global__ __launch_bounds__(256) void convert_w_kernel(const float* __restrict__ W1,
                                                        const float* __restrict__ W2,
                                                        unsigned short* __restrict__ w1t,
                                                        unsigned short* __restrict__ w2t) {
    int idx = blockIdx.x * 256 + threadIdx.x;
    if (idx < 65536) {
        int n = idx >> 8, k = idx & 255;
        w1t[idx] = f2bf(W1[k * 256 + n]);
    } else {
        int i2 = idx - 65536;               // < 262144
        int n = i2 >> 8, k = i2 & 255;
        w2t[i2] = f2bf(W2[k * 1024 + n]);
    }
}

// ---- distance GEMM + per-slice argmin: 128 tokens x 128 codes per block ----
// FMA chain per (token,code): k ascending (dc,dq,x,y,z,w) == np BLAS sequential chain.
// dist = fl(fl(A - 2*acc) + C); ties -> lowest index everywhere.
__global__ __launch_bounds__(256) void vq_main(const float* __restrict__ resSrc,
                                               const float* __restrict__ Ei,
                                               const float* __restrict__ sseEi,
                                               const float* __restrict__ normA,
                                               float* __restrict__ pm1,
                                               int* __restrict__ pi1) {
    __shared__ float sRes[128 * 36];   // stride 36 words: b128 reads 2-way (free)
    __shared__ float sE[128 * 36];
    __shared__ float sA[128];
    const int tid = threadIdx.x;
    const int tx = tid & 15, ty = tid >> 4;
    const int slice = blockIdx.x & 15;
    const int tile  = blockIdx.x >> 4;
    const int t0 = tile * 128;
    const int kc = slice * 128;

    if (tid < 128) sA[tid] = normA[t0 + tid];

    float acc[8][8];
    #pragma unroll
    for (int i = 0; i < 8; ++i)
        #pragma unroll
        for (int j = 0; j < 8; ++j) acc[i][j] = 0.f;

    for (int dc = 0; dc < 8; ++dc) {
        const int db = dc * 32;
        __syncthreads();
        #pragma unroll
        for (int p = 0; p < 4; ++p) {               // 128x32 residual chunk
            int chunk = tid + p * 256;
            int tt = chunk >> 3, dq = chunk & 7;
            *(float4*)(&sRes[tt * 36 + dq * 4]) =
                *(const float4*)(resSrc + (size_t)(t0 + tt) * DDIM + db + dq * 4);
        }
        #pragma unroll
        for (int p = 0; p < 4; ++p) {               // 128x32 E chunk
            int chunk = tid + p * 256;
            int cc = chunk >> 3, dq = chunk & 7;
            *(float4*)(&sE[cc * 36 + dq * 4]) =
                *(const float4*)(Ei + (size_t)(kc + cc) * DDIM + db + dq * 4);
        }
        __syncthreads();
        #pragma unroll
        for (int dq = 0; dq < 8; ++dq) {
            float4 b[8];
            #pragma unroll
            for (int j = 0; j < 8; ++j)
                b[j] = *(const float4*)(&sE[(tx + 16 * j) * 36 + dq * 4]);
            #pragma unroll
            for (int i = 0; i < 8; ++i) {
                const float4 a = *(const float4*)(&sRes[(ty + 16 * i) * 36 + dq * 4]);
                #pragma unroll
                for (int j = 0; j < 8; ++j) {
                    acc[i][j] = fmaf(a.x, b[j].x, acc[i][j]);
                    acc[i][j] = fmaf(a.y, b[j].y, acc[i][j]);
                    acc[i][j] = fmaf(a.z, b[j].z, acc[i][j]);
                    acc[i][j] = fmaf(a.w, b[j].w, acc[i][j]);
                }
            }
        }
    }

    // per-thread argmin over 8 codes (j ascending => code ascending: first-min wins)
    float Cf[8];
    #pragma unroll
    for (int j = 0; j < 8; ++j) Cf[j] = sseEi[kc + tx + 16 * j];
    float m1[8]; int i1[8];
    #pragma unroll
    for (int i = 0; i < 8; ++i) { m1[i] = FLT_MAX; i1[i] = 0x7fffffff; }
    #pragma unroll
    for (int i = 0; i < 8; ++i) {
        const float A = sA[ty + 16 * i];
        #pragma unroll
        for (int j = 0; j < 8; ++j) {
            float d1 = fmaf(-2.f, acc[i][j], A);     // == fl(A - X2)
            float s  = __fadd_rn(d1, Cf[j]);         // quantized dist
            int c = kc + tx + 16 * j;
            if (s < m1[i]) { m1[i] = s; i1[i] = c; }
        }
    }

    float* sM1 = sRes;                 // 128*17 floats, fits
    int*   sI1 = (int*)sE;
    __syncthreads();
    #pragma unroll
    for (int i = 0; i < 8; ++i) {
        int t = ty + 16 * i;
        sM1[t * 17 + tx] = m1[i];
        sI1[t * 17 + tx] = i1[i];
    }
    __syncthreads();
    if (tid < 128) {
        int t = tid;
        float gm1 = FLT_MAX; int gi1 = 0x7fffffff;
        for (int x = 0; x < 16; ++x) {
            float v1 = sM1[t * 17 + x];
            int ii = sI1[t * 17 + x];
            if (v1 < gm1 || (v1 == gm1 && ii < gi1)) { gm1 = v1; gi1 = ii; }
        }
        size_t o = (size_t)(t0 + t) * 16 + slice;
        pm1[o] = gm1; pi1[o] = gi1;
    }
}

// ---- merge 16 slices; exact f32 chain update; fused np-exact next-iter norm;
//      on iter 0 also emit zq as bf16 for the MFMA semantic head ----
__global__ __launch_bounds__(256) void vq_finalize(const float* __restrict__ z,
                                                   const float* __restrict__ Ei,
                                                   float* __restrict__ res,
                                                   float* __restrict__ zq,
                                                   float* __restrict__ codes,
                                                   float* __restrict__ vql,
                                                   float* __restrict__ normA,
                                                   unsigned short* __restrict__ zqb,
                                                   const float* __restrict__ pm1,
                                                   const int* __restrict__ pi1,
                                                   int iter) {
    __shared__ int sIdx[64];
    __shared__ float sRed[4];
    __shared__ float sScr[4][256];
    const int tid = threadIdx.x;
    const int t0 = blockIdx.x * 64;

    if (tid < 64) {
        float m1 = FLT_MAX; int i1 = 0x7fffffff;
        size_t base = (size_t)(t0 + tid) * 16;
        for (int s = 0; s < 16; ++s) {
            float v = pm1[base + s]; int ii = pi1[base + s];
            if (v < m1 || (v == m1 && ii < i1)) { m1 = v; i1 = ii; }
        }
        sIdx[tid] = i1;
        codes[(size_t)(t0 + tid) * NCB + iter] = (float)i1;
    }
    __syncthreads();

    const int w = tid >> 6, l = tid & 63;
    const int half = (l & 15) >> 3, j = l & 7;       // for norm phase (lanes<16 of each wave)
    float lsum = 0.f;
    for (int s = 0; s < 16; ++s) {
        const int tt = w * 16 + s;
        const int t = t0 + tt;
        const size_t go = (size_t)t * DDIM + l * 4;
        const int idx = sIdx[tt];
        const float4 r4 = (iter == 0) ? *(const float4*)(z + go) : *(const float4*)(res + go);
        const float4 q4 = *(const float4*)(Ei + (size_t)idx * DDIM + l * 4);
        float4 rn4, zqi4;
        // reference elementwise f32: tq = fl(q-r); z_q = fl(r+tq); r' = fl(r-z_q)
        float tqx = q4.x - r4.x; zqi4.x = r4.x + tqx; rn4.x = r4.x - zqi4.x;
        float tqy = q4.y - r4.y; zqi4.y = r4.y + tqy; rn4.y = r4.y - zqi4.y;
        float tqz = q4.z - r4.z; zqi4.z = r4.z + tqz; rn4.z = r4.z - zqi4.z;
        float tqw = q4.w - r4.w; zqi4.w = r4.w + tqw; rn4.w = r4.w - zqi4.w;
        lsum = fmaf(tqx, tqx, lsum); lsum = fmaf(tqy, tqy, lsum);
        lsum = fmaf(tqz, tqz, lsum); lsum = fmaf(tqw, tqw, lsum);
        *(float4*)(res + go) = rn4;
        if (iter == 0) {
            *(float4*)(zq + go) = zqi4;
            unsigned short u[4] = { f2bf(zqi4.x), f2bf(zqi4.y), f2bf(zqi4.z), f2bf(zqi4.w) };
            *(ushort4*)(zqb + go) = *(ushort4*)u;
        } else {
            float4 o4 = *(float4*)(zq + go);
            o4.x += zqi4.x; o4.y += zqi4.y; o4.z += zqi4.z; o4.w += zqi4.w;
            *(float4*)(zq + go) = o4;
        }
        // fused np-exact norm of rn for next iter (in-wave LDS round-trip)
        *(float4*)(&sScr[w][l * 4]) = rn4;
        if (l < 16) {
            const float* a = &sScr[w][half * 128 + j];
            float v = a[0];
            float r = __fmul_rn(v, v);
            #pragma unroll
            for (int k = 1; k < 16; ++k) { v = a[k * 8]; r = __fadd_rn(r, __fmul_rn(v, v)); }
            r = __fadd_rn(r, __shfl_xor(r, 1, 64));
            r = __fadd_rn(r, __shfl_xor(r, 2, 64));
            r = __fadd_rn(r, __shfl_xor(r, 4, 64));
            r = __fadd_rn(r, __shfl_xor(r, 8, 64));
            if (l == 0) normA[t] = r;
        }
    }

    #pragma unroll
    for (int o = 32; o >= 1; o >>= 1) lsum += __shfl_xor(lsum, o, 64);
    if (l == 0) sRed[w] = lsum;
    __syncthreads();
    if (tid == 0)
        atomicAdd(vql, (sRed[0] + sRed[1] + sRed[2] + sRed[3]) * (1.25f / 4194304.f));
}

// ---- semantic head, bf16 MFMA: zq@W1 -> GELU -> @W2 -> MSE (loss tolerance is huge) --
// 32 tokens/block, 256 threads (4 waves). mfma_f32_16x16x32_bf16:
// A[m=lane&15][k=quad*8+j], B[n=lane&15][k=quad*8+j], C/D col=lane&15,row=quad*4+reg.
__global__ __launch_bounds__(256) void semantic_mfma(const unsigned short* __restrict__ zqb,
                                                     const float* __restrict__ tgt,
                                                     const unsigned short* __restrict__ w1t,
                                                     const float* __restrict__ b1,
                                                     const unsigned short* __restrict__ w2t,
                                                     const float* __restrict__ b2,
                                                     float* __restrict__ semLoss) {
    __shared__ unsigned short sZ[32 * 264];   // stride 264: 16B-aligned rows, low conflict
    __shared__ unsigned short sH[32 * 264];
    __shared__ float sRed[4];
    const int tid = threadIdx.x;
    const int wv = tid >> 6, lane = tid & 63;
    const int l15 = lane & 15, qd = lane >> 4;
    const int tb = blockIdx.x * 32;

    {   // stage 32x256 bf16 zq tile
        int row = tid >> 3, seg = tid & 7;
        const uint4* src = (const uint4*)(zqb + (size_t)(tb + row) * 256);
        uint4* dst = (uint4*)(&sZ[row * 264]);
        #pragma unroll
        for (int p = 0; p < 4; ++p) dst[seg * 4 + p] = src[seg * 4 + p];
    }
    __syncthreads();

    short8 az[8][2];
    #pragma unroll
    for (int kc = 0; kc < 8; ++kc)
        #pragma unroll
        for (int m = 0; m < 2; ++m)
            az[kc][m] = *(const short8*)(&sZ[(16 * m + l15) * 264 + kc * 32 + qd * 8]);

    // GEMM1 + bias + GELU -> sH (each wave: 4 n-tiles)
    #pragma unroll
    for (int nt4 = 0; nt4 < 4; ++nt4) {
        const int nt = wv * 4 + nt4;
        f32x4 acc0 = {0.f,0.f,0.f,0.f}, acc1 = {0.f,0.f,0.f,0.f};
        const unsigned short* bb = w1t + (size_t)(16 * nt + l15) * 256 + qd * 8;
        #pragma unroll
        for (int kc = 0; kc < 8; ++kc) {
            short8 b = *(const short8*)(bb + kc * 32);
            acc0 = __builtin_amdgcn_mfma_f32_16x16x32_bf16(az[kc][0], b, acc0, 0, 0, 0);
            acc1 = __builtin_amdgcn_mfma_f32_16x16x32_bf16(az[kc][1], b, acc1, 0, 0, 0);
        }
        const float b1v = b1[16 * nt + l15];
        #pragma unroll
        for (int r = 0; r < 4; ++r) {
            float x0 = acc0[r] + b1v;
            float x1 = acc1[r] + b1v;
            sH[(4 * qd + r) * 264 + 16 * nt + l15]        = f2bf(0.5f * x0 * (1.f + erff(x0 * 0.70710678f)));
            sH[(16 + 4 * qd + r) * 264 + 16 * nt + l15]   = f2bf(0.5f * x1 * (1.f + erff(x1 * 0.70710678f)));
        }
    }
    __syncthreads();

    short8 ah[8][2];
    #pragma unroll
    for (int kc = 0; kc < 8; ++kc)
        #pragma unroll
        for (int m = 0; m < 2; ++m)
            ah[kc][m] = *(const short8*)(&sH[(16 * m + l15) * 264 + kc * 32 + qd * 8]);

    // GEMM2 + bias + MSE (each wave: 16 n-tiles of 64)
    float lsum = 0.f;
    for (int t = 0; t < 16; ++t) {
        const int nt = wv * 16 + t;
        f32x4 acc0 = {0.f,0.f,0.f,0.f}, acc1 = {0.f,0.f,0.f,0.f};
        const unsigned short* bb = w2t + (size_t)(16 * nt + l15) * 256 + qd * 8;
        #pragma unroll
        for (int kc = 0; kc < 8; ++kc) {
            short8 b = *(const short8*)(bb + kc * 32);
            acc0 = __builtin_amdgcn_mfma_f32_16x16x32_bf16(ah[kc][0], b, acc0, 0, 0, 0);
            acc1 = __builtin_amdgcn_mfma_f32_16x16x32_bf16(ah[kc][1], b, acc1, 0, 0, 0);
        }
        const int n = 16 * nt + l15;
        const float b2v = b2[n];
        #pragma unroll
        for (int r = 0; r < 4; ++r) {
            float dv0 = (acc0[r] + b2v) - tgt[(size_t)(tb + 4 * qd + r) * 1024 + n];
            float dv1 = (acc1[r] + b2v) - tgt[(size_t)(tb + 16 + 4 * qd + r) * 1024 + n];
            lsum = fmaf(dv0, dv0, lsum);
            lsum = fmaf(dv1, dv1, lsum);
        }
    }
    #pragma unroll
    for (int o = 32; o >= 1; o >>= 1) lsum += __shfl_xor(lsum, o, 64);
    if (lane == 0) sRed[wv] = lsum;
    __syncthreads();
    if (tid == 0)
        atomicAdd(semLoss, (sRed[0] + sRed[1] + sRed[2] + sRed[3]) * (1.0f / 16777216.f));
}

extern "C" void kernel_launch(void* const* d_in, const int* in_sizes, int n_in,
                              void* d_out, int out_size, void* d_ws, size_t ws_size,
                              hipStream_t stream) {
    const float* z   = (const float*)d_in[0];
    const float* tgt = (const float*)d_in[1];
    const float* E   = (const float*)d_in[2];
    const float* W1  = (const float*)d_in[3];
    const float* b1  = (const float*)d_in[4];
    const float* W2  = (const float*)d_in[5];
    const float* b2  = (const float*)d_in[6];

    float* out   = (float*)d_out;
    float* zq    = out;
    float* codes = out + (size_t)NTOK * DDIM;
    float* vql   = codes + (size_t)NTOK * NCB;       // [vq_loss, semantic_loss]

    char* w = (char*)d_ws;
    float*          res   = (float*)(w);                        // 16 MiB
    unsigned short* zqb   = (unsigned short*)(w + 16777216);    // 8 MiB
    float*          pm1   = (float*)(w + 25165824);             // 1 MiB
    int*            pi1   = (int*)  (w + 26214400);             // 1 MiB
    float*          sseE  = (float*)(w + 27262976);             // 80 KiB (pad 128K)
    float*          normA = (float*)(w + 27394048);             // 64 KiB (pad 128K)
    unsigned short* w1t   = (unsigned short*)(w + 27525120);    // 128 KiB
    unsigned short* w2t   = (unsigned short*)(w + 27656192);    // 512 KiB

    hipMemsetAsync(vql, 0, 2 * sizeof(float), stream);
    norms_all_kernel<<<9216, 256, 0, stream>>>(E, z, sseE, normA);
    convert_w_kernel<<<1280, 256, 0, stream>>>(W1, W2, w1t, w2t);
    for (int it = 0; it < NCB; ++it) {
        const float* Ei    = E + (size_t)it * KCB * DDIM;
        const float* sseEi = sseE + (size_t)it * KCB;
        const float* resSrc = (it == 0) ? z : res;
        vq_main<<<2048, 256, 0, stream>>>(resSrc, Ei, sseEi, normA, pm1, pi1);
        vq_finalize<<<256, 256, 0, stream>>>(z, Ei, res, zq, codes, vql, normA, zqb,
                                             pm1, pi1, it);
        if (it == 0)
            semantic_mfma<<<512, 256, 0, stream>>>(zqb, tgt, w1t, b1, w2t, b2, vql + 1);
    }
}

// Round 5
// 2338.087 us; speedup vs baseline: 1.2339x; 1.1447x over previous
//
#include <hip/hip_runtime.h>
#include <float.h>
#include <math.h>

#define NTOK 16384
#define KCB  2048
#define DDIM 256
#define NCB  10
#define MARGIN 2.5e-4f

typedef __attribute__((ext_vector_type(8))) short  short8;
typedef __attribute__((ext_vector_type(4))) float  f32x4;

static __device__ __forceinline__ unsigned short f2bf(float f) {
    unsigned int b = __float_as_uint(f);
    unsigned int r = b + 0x7FFFu + ((b >> 16) & 1u);   // RNE
    return (unsigned short)(r >> 16);
}
static __device__ __forceinline__ float bf2f(unsigned short h) {
    return __uint_as_float((unsigned int)h << 16);
}

// ---- np-bit-exact pairwise sum of squares (rows of 256): E rows + z rows ----
__global__ __launch_bounds__(256) void norms_all_kernel(const float* __restrict__ E,
                                                        const float* __restrict__ z,
                                                        float* __restrict__ sseE,
                                                        float* __restrict__ normA) {
    const int gw   = (blockIdx.x * 256 + threadIdx.x) >> 6;
    const int lane = threadIdx.x & 63;
    const int row  = gw * 4 + (lane >> 4);
    const int l    = lane & 15;
    const float* src = nullptr; float* dst = nullptr;
    if (row < NCB * KCB)             { src = E + (size_t)row * DDIM;               dst = sseE + row; }
    else if (row < NCB * KCB + NTOK) { src = z + (size_t)(row - NCB * KCB) * DDIM; dst = normA + (row - NCB * KCB); }
    float r = 0.f;
    if (src) {
        const float* a = src + ((l >> 3) << 7) + (l & 7);
        float v = a[0];
        r = __fmul_rn(v, v);
        #pragma unroll
        for (int k = 1; k < 16; ++k) { v = a[k * 8]; r = __fadd_rn(r, __fmul_rn(v, v)); }
    }
    r = __fadd_rn(r, __shfl_xor(r, 1, 64));
    r = __fadd_rn(r, __shfl_xor(r, 2, 64));
    r = __fadd_rn(r, __shfl_xor(r, 4, 64));
    r = __fadd_rn(r, __shfl_xor(r, 8, 64));
    if (src && l == 0) *dst = r;
}

// ---- convert: E -> (Eh,El) bf16 hi/lo; z -> (resH,resL); W1/W2 -> transposed bf16 ----
__global__ __launch_bounds__(256) void conv_all_kernel(const float* __restrict__ E,
                                                       const float* __restrict__ z,
                                                       const float* __restrict__ W1,
                                                       const float* __restrict__ W2,
                                                       unsigned short* __restrict__ Eh,
                                                       unsigned short* __restrict__ El,
                                                       unsigned short* __restrict__ resH,
                                                       unsigned short* __restrict__ resL,
                                                       unsigned short* __restrict__ w1t,
                                                       unsigned short* __restrict__ w2t) {
    int i = blockIdx.x * 256 + threadIdx.x;
    if (i < 5242880) {
        float f = E[i];
        unsigned short h = f2bf(f);
        Eh[i] = h; El[i] = f2bf(f - bf2f(h));
    } else if (i < 9437184) {
        int j = i - 5242880;
        float f = z[j];
        unsigned short h = f2bf(f);
        resH[j] = h; resL[j] = f2bf(f - bf2f(h));
    } else if (i < 9502720) {
        int j = i - 9437184;
        int n = j >> 8, k = j & 255;
        w1t[j] = f2bf(W1[k * 256 + n]);
    } else {
        int j = i - 9502720;
        int n = j >> 8, k = j & 255;
        w2t[j] = f2bf(W2[k * 1024 + n]);
    }
}

// ---- MFMA screening: 128 tokens x 128 codes per block; hi/lo bf16 split (3 MFMAs) ----
// approx score = C_c - 2*dotApprox; per-token slice min + candidates within MARGIN.
// Rigorous: |approx - exact| <= ~7e-6 in dist units; quantized-compare slop 6.6e-5 << M.
__global__ __launch_bounds__(256) void vq_screen(const unsigned short* __restrict__ resH,
                                                 const unsigned short* __restrict__ resL,
                                                 const unsigned short* __restrict__ Ehi,
                                                 const unsigned short* __restrict__ Eli,
                                                 const float* __restrict__ sseEi,
                                                 int2* __restrict__ gSlots,
                                                 int* __restrict__ gCnt) {
    __shared__ unsigned short sAh[128 * 40], sAl[128 * 40];   // stride 40 shorts: rows r,r+8
    __shared__ unsigned short sBh[128 * 40], sBl[128 * 40];   // share bank group -> 2-way (free)
    __shared__ float sC[128];
    __shared__ int   lCnt[128];
    __shared__ int2  lSlot[128][4];
    const int tid = threadIdx.x;
    const int wv = tid >> 6, lane = tid & 63;
    const int l15 = lane & 15, qd = lane >> 4;
    const int tile = blockIdx.x >> 4, slice = blockIdx.x & 15;
    const int t0 = tile * 128, c0 = slice * 128;

    if (tid < 128) { lCnt[tid] = 0; sC[tid] = sseEi[c0 + tid]; }
    {
        int2 inf; inf.x = 0x7F800000; inf.y = 0;
        ((int2*)lSlot)[tid] = inf; ((int2*)lSlot)[tid + 256] = inf;
    }

    f32x4 acc[2][8];
    #pragma unroll
    for (int m = 0; m < 2; ++m)
        #pragma unroll
        for (int n = 0; n < 8; ++n) acc[m][n] = (f32x4){0.f, 0.f, 0.f, 0.f};

    const int r0 = tid >> 2, c0c = tid & 3;        // staging coords (idx = tid)
    const int r1 = (tid + 256) >> 2, c1c = tid & 3;
    for (int kc = 0; kc < 8; ++kc) {
        const int db = kc * 32;
        __syncthreads();
        // 4 planes x 512 16B-chunks; plane is compile-time per p
        *(uint4*)(sAh + r0 * 40 + c0c * 8) = *(const uint4*)(resH + (size_t)(t0 + r0) * 256 + db + c0c * 8);
        *(uint4*)(sAh + r1 * 40 + c1c * 8) = *(const uint4*)(resH + (size_t)(t0 + r1) * 256 + db + c1c * 8);
        *(uint4*)(sAl + r0 * 40 + c0c * 8) = *(const uint4*)(resL + (size_t)(t0 + r0) * 256 + db + c0c * 8);
        *(uint4*)(sAl + r1 * 40 + c1c * 8) = *(const uint4*)(resL + (size_t)(t0 + r1) * 256 + db + c1c * 8);
        *(uint4*)(sBh + r0 * 40 + c0c * 8) = *(const uint4*)(Ehi  + (size_t)(c0 + r0) * 256 + db + c0c * 8);
        *(uint4*)(sBh + r1 * 40 + c1c * 8) = *(const uint4*)(Ehi  + (size_t)(c0 + r1) * 256 + db + c1c * 8);
        *(uint4*)(sBl + r0 * 40 + c0c * 8) = *(const uint4*)(Eli  + (size_t)(c0 + r0) * 256 + db + c0c * 8);
        *(uint4*)(sBl + r1 * 40 + c1c * 8) = *(const uint4*)(Eli  + (size_t)(c0 + r1) * 256 + db + c1c * 8);
        __syncthreads();

        short8 ah[2], al[2];
        #pragma unroll
        for (int m = 0; m < 2; ++m) {
            int off = (wv * 32 + m * 16 + l15) * 40 + qd * 8;
            ah[m] = *(const short8*)(sAh + off);
            al[m] = *(const short8*)(sAl + off);
        }
        #pragma unroll
        for (int n = 0; n < 8; ++n) {
            int off = (n * 16 + l15) * 40 + qd * 8;
            short8 bh = *(const short8*)(sBh + off);
            short8 bl = *(const short8*)(sBl + off);
            #pragma unroll
            for (int m = 0; m < 2; ++m) {
                acc[m][n] = __builtin_amdgcn_mfma_f32_16x16x32_bf16(al[m], bh, acc[m][n], 0, 0, 0);
                acc[m][n] = __builtin_amdgcn_mfma_f32_16x16x32_bf16(ah[m], bl, acc[m][n], 0, 0, 0);
                acc[m][n] = __builtin_amdgcn_mfma_f32_16x16x32_bf16(ah[m], bh, acc[m][n], 0, 0, 0);
            }
        }
    }

    // scores in place: s = C - 2*dot
    #pragma unroll
    for (int m = 0; m < 2; ++m)
        #pragma unroll
        for (int n = 0; n < 8; ++n) {
            float Cv = sC[n * 16 + l15];
            #pragma unroll
            for (int r = 0; r < 4; ++r) acc[m][n][r] = fmaf(-2.f, acc[m][n][r], Cv);
        }
    // per-token slice min (reduce over n, then over the 16 code-lanes)
    float tmin[2][4];
    #pragma unroll
    for (int m = 0; m < 2; ++m)
        #pragma unroll
        for (int r = 0; r < 4; ++r) {
            float v = acc[m][0][r];
            #pragma unroll
            for (int n = 1; n < 8; ++n) v = fminf(v, acc[m][n][r]);
            v = fminf(v, __shfl_xor(v, 1, 64));
            v = fminf(v, __shfl_xor(v, 2, 64));
            v = fminf(v, __shfl_xor(v, 4, 64));
            v = fminf(v, __shfl_xor(v, 8, 64));
            tmin[m][r] = v;
        }
    // push candidates within MARGIN of slice min (wave-private tokens; rare)
    #pragma unroll
    for (int m = 0; m < 2; ++m)
        #pragma unroll
        for (int r = 0; r < 4; ++r) {
            int tloc = wv * 32 + m * 16 + qd * 4 + r;
            float thr = tmin[m][r] + MARGIN;
            #pragma unroll
            for (int n = 0; n < 8; ++n) {
                float sv = acc[m][n][r];
                if (sv <= thr) {
                    int pos = atomicAdd(&lCnt[tloc], 1);
                    if (pos < 4) {
                        int2 e; e.x = __float_as_int(sv); e.y = c0 + n * 16 + l15;
                        lSlot[tloc][pos] = e;
                    }
                }
            }
        }
    __syncthreads();
    {
        int tloc = tid >> 1, half = tid & 1;
        size_t base = (size_t)(t0 + tloc) * 64 + slice * 4 + half * 2;
        gSlots[base]     = lSlot[tloc][half * 2];
        gSlots[base + 1] = lSlot[tloc][half * 2 + 1];
        if (!half) gCnt[(t0 + tloc) * 16 + slice] = lCnt[tloc];
    }
}

// ---- exact np chain for one (token,code): sequential ascending-k f32 FMA ----
static __device__ __forceinline__ float np_chain(const float* __restrict__ sRow,
                                                 const float* __restrict__ Ei,
                                                 int cc, float A, float C) {
    const float4* e = (const float4*)(Ei + (size_t)cc * DDIM);
    float a = 0.f;
    #pragma unroll 8
    for (int k = 0; k < 64; ++k) {
        float4 ev = e[k];
        const float4 rv = *(const float4*)(sRow + k * 4);
        a = fmaf(rv.x, ev.x, a); a = fmaf(rv.y, ev.y, a);
        a = fmaf(rv.z, ev.z, a); a = fmaf(rv.w, ev.w, a);
    }
    return __fadd_rn(fmaf(-2.f, a, A), C);
}

// ---- per-token: merge slices, repair if ambiguous, exact f32 chain update, norms ----
// one wave per token; block 256 = 4 tokens.
__global__ __launch_bounds__(256) void vq_post(const float* __restrict__ resSrc,
                                               const float* __restrict__ Ei,
                                               const float* __restrict__ sseEi,
                                               float* __restrict__ res,
                                               float* __restrict__ zq,
                                               float* __restrict__ codes,
                                               float* __restrict__ lossTok,
                                               float* __restrict__ normA,
                                               unsigned short* __restrict__ resHp,
                                               unsigned short* __restrict__ resLp,
                                               unsigned short* __restrict__ zqb,
                                               const int2* __restrict__ gSlots,
                                               const int* __restrict__ gCnt,
                                               int iter) {
    __shared__ float sScr[4][256];
    const int tid = threadIdx.x;
    const int wv = tid >> 6, lane = tid & 63;
    const int t = blockIdx.x * 4 + wv;

    const float4 r4 = *(const float4*)(resSrc + (size_t)t * DDIM + lane * 4);
    *(float4*)(&sScr[wv][lane * 4]) = r4;
    __syncthreads();                       // block-wide, before any divergent per-wave path

    int2 sl = gSlots[(size_t)t * 64 + lane];
    float sv = __int_as_float(sl.x);
    int sidx = sl.y;
    int cnt = (lane < 16) ? gCnt[t * 16 + lane] : 0;
    const int ovf = __any(cnt > 4);
    float gm = sv;
    #pragma unroll
    for (int o = 32; o >= 1; o >>= 1) gm = fminf(gm, __shfl_xor(gm, o, 64));
    const bool active = (sv <= gm + MARGIN);
    unsigned long long bal = __ballot(active ? 1 : 0);
    const float A = normA[t];

    int winner;
    if (!ovf && __popcll(bal) == 1) {
        winner = __shfl(sidx, __ffsll(bal) - 1, 64);
    } else {
        unsigned long long best = ~0ULL;
        if (ovf) {
            for (int cc = lane; cc < KCB; cc += 64) {
                float s = np_chain(sScr[wv], Ei, cc, A, sseEi[cc]);
                unsigned long long key = ((unsigned long long)__float_as_uint(s) << 32) | (unsigned)cc;
                if (key < best) best = key;
            }
        } else if (active) {
            float s = np_chain(sScr[wv], Ei, sidx, A, sseEi[sidx]);
            best = ((unsigned long long)__float_as_uint(s) << 32) | (unsigned)sidx;
        }
        #pragma unroll
        for (int o = 32; o >= 1; o >>= 1) {
            unsigned long long ot = __shfl_xor(best, o, 64);
            if (ot < best) best = ot;
        }
        winner = (int)(unsigned)(best & 0xFFFFFFFFu);
    }
    if (lane == 0) codes[(size_t)t * NCB + iter] = (float)winner;

    // exact elementwise f32 chain update
    const size_t go = (size_t)t * DDIM + lane * 4;
    const float4 q4 = *(const float4*)(Ei + (size_t)winner * DDIM + lane * 4);
    float4 rn4, zqi4;
    float tqx = q4.x - r4.x; zqi4.x = r4.x + tqx; rn4.x = r4.x - zqi4.x;
    float tqy = q4.y - r4.y; zqi4.y = r4.y + tqy; rn4.y = r4.y - zqi4.y;
    float tqz = q4.z - r4.z; zqi4.z = r4.z + tqz; rn4.z = r4.z - zqi4.z;
    float tqw = q4.w - r4.w; zqi4.w = r4.w + tqw; rn4.w = r4.w - zqi4.w;
    float lsum = 0.f;
    lsum = fmaf(tqx, tqx, lsum); lsum = fmaf(tqy, tqy, lsum);
    lsum = fmaf(tqz, tqz, lsum); lsum = fmaf(tqw, tqw, lsum);
    *(float4*)(res + go) = rn4;
    {   // bf16 hi/lo planes for next screen
        unsigned short hx = f2bf(rn4.x), hy = f2bf(rn4.y), hz = f2bf(rn4.z), hw = f2bf(rn4.w);
        unsigned short h[4] = { hx, hy, hz, hw };
        unsigned short lo[4] = { f2bf(rn4.x - bf2f(hx)), f2bf(rn4.y - bf2f(hy)),
                                 f2bf(rn4.z - bf2f(hz)), f2bf(rn4.w - bf2f(hw)) };
        *(ushort4*)(resHp + go) = *(ushort4*)h;
        *(ushort4*)(resLp + go) = *(ushort4*)lo;
    }
    if (iter == 0) {
        *(float4*)(zq + go) = zqi4;
        unsigned short u[4] = { f2bf(zqi4.x), f2bf(zqi4.y), f2bf(zqi4.z), f2bf(zqi4.w) };
        *(ushort4*)(zqb + go) = *(ushort4*)u;
    } else {
        float4 o4 = *(float4*)(zq + go);
        o4.x += zqi4.x; o4.y += zqi4.y; o4.z += zqi4.z; o4.w += zqi4.w;
        *(float4*)(zq + go) = o4;
    }
    // np-exact norm of new residual (verified association)
    *(float4*)(&sScr[wv][lane * 4]) = rn4;
    if (lane < 16) {
        const int half = lane >> 3, j = lane & 7;
        const float* a = &sScr[wv][half * 128 + j];
        float v = a[0];
        float r = __fmul_rn(v, v);
        #pragma unroll
        for (int k = 1; k < 16; ++k) { v = a[k * 8]; r = __fadd_rn(r, __fmul_rn(v, v)); }
        r = __fadd_rn(r, __shfl_xor(r, 1, 64));
        r = __fadd_rn(r, __shfl_xor(r, 2, 64));
        r = __fadd_rn(r, __shfl_xor(r, 4, 64));
        r = __fadd_rn(r, __shfl_xor(r, 8, 64));
        if (lane == 0) normA[t] = r;
    }
    #pragma unroll
    for (int o = 32; o >= 1; o >>= 1) lsum += __shfl_xor(lsum, o, 64);
    if (lane == 0) lossTok[t] = (iter == 0) ? lsum : (lossTok[t] + lsum);
}

// ---- vq loss finalize ----
__global__ __launch_bounds__(256) void loss_final(const float* __restrict__ lossTok,
                                                  float* __restrict__ vql) {
    __shared__ float sRed[4];
    float s = 0.f;
    for (int i = threadIdx.x; i < NTOK; i += 256) s += lossTok[i];
    #pragma unroll
    for (int o = 32; o >= 1; o >>= 1) s += __shfl_xor(s, o, 64);
    if ((threadIdx.x & 63) == 0) sRed[threadIdx.x >> 6] = s;
    __syncthreads();
    if (threadIdx.x == 0)
        vql[0] = (sRed[0] + sRed[1] + sRed[2] + sRed[3]) * (1.25f / 4194304.f);
}

// ---- semantic head, bf16 MFMA (unchanged from round 4; loss tolerance is huge) ----
__global__ __launch_bounds__(256) void semantic_mfma(const unsigned short* __restrict__ zqb,
                                                     const float* __restrict__ tgt,
                                                     const unsigned short* __restrict__ w1t,
                                                     const float* __restrict__ b1,
                                                     const unsigned short* __restrict__ w2t,
                                                     const float* __restrict__ b2,
                                                     float* __restrict__ semLoss) {
    __shared__ unsigned short sZ[32 * 264];
    __shared__ unsigned short sH[32 * 264];
    __shared__ float sRed[4];
    const int tid = threadIdx.x;
    const int wv = tid >> 6, lane = tid & 63;
    const int l15 = lane & 15, qd = lane >> 4;
    const int tb = blockIdx.x * 32;

    {
        int row = tid >> 3, seg = tid & 7;
        const uint4* src = (const uint4*)(zqb + (size_t)(tb + row) * 256);
        uint4* dst = (uint4*)(&sZ[row * 264]);
        #pragma unroll
        for (int p = 0; p < 4; ++p) dst[seg * 4 + p] = src[seg * 4 + p];
    }
    __syncthreads();

    short8 az[8][2];
    #pragma unroll
    for (int kc = 0; kc < 8; ++kc)
        #pragma unroll
        for (int m = 0; m < 2; ++m)
            az[kc][m] = *(const short8*)(&sZ[(16 * m + l15) * 264 + kc * 32 + qd * 8]);

    #pragma unroll
    for (int nt4 = 0; nt4 < 4; ++nt4) {
        const int nt = wv * 4 + nt4;
        f32x4 acc0 = {0.f,0.f,0.f,0.f}, acc1 = {0.f,0.f,0.f,0.f};
        const unsigned short* bb = w1t + (size_t)(16 * nt + l15) * 256 + qd * 8;
        #pragma unroll
        for (int kc = 0; kc < 8; ++kc) {
            short8 b = *(const short8*)(bb + kc * 32);
            acc0 = __builtin_amdgcn_mfma_f32_16x16x32_bf16(az[kc][0], b, acc0, 0, 0, 0);
            acc1 = __builtin_amdgcn_mfma_f32_16x16x32_bf16(az[kc][1], b, acc1, 0, 0, 0);
        }
        const float b1v = b1[16 * nt + l15];
        #pragma unroll
        for (int r = 0; r < 4; ++r) {
            float x0 = acc0[r] + b1v;
            float x1 = acc1[r] + b1v;
            sH[(4 * qd + r) * 264 + 16 * nt + l15]      = f2bf(0.5f * x0 * (1.f + erff(x0 * 0.70710678f)));
            sH[(16 + 4 * qd + r) * 264 + 16 * nt + l15] = f2bf(0.5f * x1 * (1.f + erff(x1 * 0.70710678f)));
        }
    }
    __syncthreads();

    short8 ah[8][2];
    #pragma unroll
    for (int kc = 0; kc < 8; ++kc)
        #pragma unroll
        for (int m = 0; m < 2; ++m)
            ah[kc][m] = *(const short8*)(&sH[(16 * m + l15) * 264 + kc * 32 + qd * 8]);

    float lsum = 0.f;
    for (int t = 0; t < 16; ++t) {
        const int nt = wv * 16 + t;
        f32x4 acc0 = {0.f,0.f,0.f,0.f}, acc1 = {0.f,0.f,0.f,0.f};
        const unsigned short* bb = w2t + (size_t)(16 * nt + l15) * 256 + qd * 8;
        #pragma unroll
        for (int kc = 0; kc < 8; ++kc) {
            short8 b = *(const short8*)(bb + kc * 32);
            acc0 = __builtin_amdgcn_mfma_f32_16x16x32_bf16(ah[kc][0], b, acc0, 0, 0, 0);
            acc1 = __builtin_amdgcn_mfma_f32_16x16x32_bf16(ah[kc][1], b, acc1, 0, 0, 0);
        }
        const int n = 16 * nt + l15;
        const float b2v = b2[n];
        #pragma unroll
        for (int r = 0; r < 4; ++r) {
            float dv0 = (acc0[r] + b2v) - tgt[(size_t)(tb + 4 * qd + r) * 1024 + n];
            float dv1 = (acc1[r] + b2v) - tgt[(size_t)(tb + 16 + 4 * qd + r) * 1024 + n];
            lsum = fmaf(dv0, dv0, lsum);
            lsum = fmaf(dv1, dv1, lsum);
        }
    }
    #pragma unroll
    for (int o = 32; o >= 1; o >>= 1) lsum += __shfl_xor(lsum, o, 64);
    if (lane == 0) sRed[wv] = lsum;
    __syncthreads();
    if (tid == 0)
        atomicAdd(semLoss, (sRed[0] + sRed[1] + sRed[2] + sRed[3]) * (1.0f / 16777216.f));
}

extern "C" void kernel_launch(void* const* d_in, const int* in_sizes, int n_in,
                              void* d_out, int out_size, void* d_ws, size_t ws_size,
                              hipStream_t stream) {
    const float* z   = (const float*)d_in[0];
    const float* tgt = (const float*)d_in[1];
    const float* E   = (const float*)d_in[2];
    const float* W1  = (const float*)d_in[3];
    const float* b1  = (const float*)d_in[4];
    const float* W2  = (const float*)d_in[5];
    const float* b2  = (const float*)d_in[6];

    float* out   = (float*)d_out;
    float* zq    = out;
    float* codes = out + (size_t)NTOK * DDIM;
    float* vql   = codes + (size_t)NTOK * NCB;       // [vq_loss, semantic_loss]

    char* w = (char*)d_ws;
    float*          res   = (float*)(w);                         // 16 MiB
    unsigned short* resH  = (unsigned short*)(w + 16777216);     // 8 MiB
    unsigned short* resL  = (unsigned short*)(w + 25165824);     // 8 MiB
    unsigned short* Eh    = (unsigned short*)(w + 33554432);     // 10 MiB
    unsigned short* El    = (unsigned short*)(w + 44040192);     // 10 MiB
    unsigned short* zqb   = (unsigned short*)(w + 54525952);     // 8 MiB
    int2*           gSlots= (int2*)(w + 62914560);               // 8 MiB (16384*64*8)
    int*            gCnt  = (int*)(w + 71303168);                // 1 MiB
    float*          sseE  = (float*)(w + 72351744);              // 80 KiB
    float*          normA = (float*)(w + 72482816);              // 64 KiB
    float*          lossTok=(float*)(w + 72613888);              // 64 KiB
    unsigned short* w1t   = (unsigned short*)(w + 72744960);     // 128 KiB
    unsigned short* w2t   = (unsigned short*)(w + 72876032);     // 512 KiB

    hipMemsetAsync(vql, 0, 2 * sizeof(float), stream);
    norms_all_kernel<<<9216, 256, 0, stream>>>(E, z, sseE, normA);
    conv_all_kernel<<<38144, 256, 0, stream>>>(E, z, W1, W2, Eh, El, resH, resL, w1t, w2t);
    for (int it = 0; it < NCB; ++it) {
        const float*          Ei    = E  + (size_t)it * KCB * DDIM;
        const unsigned short* Ehi   = Eh + (size_t)it * KCB * DDIM;
        const unsigned short* Eli   = El + (size_t)it * KCB * DDIM;
        const float*          sseEi = sseE + (size_t)it * KCB;
        const float* resSrc = (it == 0) ? z : res;
        vq_screen<<<2048, 256, 0, stream>>>(resH, resL, Ehi, Eli, sseEi, gSlots, gCnt);
        vq_post<<<4096, 256, 0, stream>>>(resSrc, Ei, sseEi, res, zq, codes, lossTok,
                                          normA, resH, resL, zqb, gSlots, gCnt, it);
        if (it == 0)
            semantic_mfma<<<512, 256, 0, stream>>>(zqb, tgt, w1t, b1, w2t, b2, vql + 1);
    }
    loss_final<<<1, 256, 0, stream>>>(lossTok, vql);
}

// Round 6
// 1664.581 us; speedup vs baseline: 1.7332x; 1.4046x over previous
//
#include <hip/hip_runtime.h>
#include <float.h>
#include <math.h>

#define NTOK 16384
#define KCB  2048
#define DDIM 256
#define NCB  10
#define MARGIN 1.0e-4f

typedef __attribute__((ext_vector_type(8))) short  short8;
typedef __attribute__((ext_vector_type(4))) float  f32x4;

static __device__ __forceinline__ unsigned short f2bf(float f) {
    unsigned int b = __float_as_uint(f);
    unsigned int r = b + 0x7FFFu + ((b >> 16) & 1u);   // RNE
    return (unsigned short)(r >> 16);
}
static __device__ __forceinline__ float bf2f(unsigned short h) {
    return __uint_as_float((unsigned int)h << 16);
}

// ---- np-bit-exact pairwise sum of squares (rows of 256): E rows + z rows ----
__global__ __launch_bounds__(256) void norms_all_kernel(const float* __restrict__ E,
                                                        const float* __restrict__ z,
                                                        float* __restrict__ sseE,
                                                        float* __restrict__ normA) {
    const int gw   = (blockIdx.x * 256 + threadIdx.x) >> 6;
    const int lane = threadIdx.x & 63;
    const int row  = gw * 4 + (lane >> 4);
    const int l    = lane & 15;
    const float* src = nullptr; float* dst = nullptr;
    if (row < NCB * KCB)             { src = E + (size_t)row * DDIM;               dst = sseE + row; }
    else if (row < NCB * KCB + NTOK) { src = z + (size_t)(row - NCB * KCB) * DDIM; dst = normA + (row - NCB * KCB); }
    float r = 0.f;
    if (src) {
        const float* a = src + ((l >> 3) << 7) + (l & 7);
        float v = a[0];
        r = __fmul_rn(v, v);
        #pragma unroll
        for (int k = 1; k < 16; ++k) { v = a[k * 8]; r = __fadd_rn(r, __fmul_rn(v, v)); }
    }
    r = __fadd_rn(r, __shfl_xor(r, 1, 64));
    r = __fadd_rn(r, __shfl_xor(r, 2, 64));
    r = __fadd_rn(r, __shfl_xor(r, 4, 64));
    r = __fadd_rn(r, __shfl_xor(r, 8, 64));
    if (src && l == 0) *dst = r;
}

// ---- convert: E -> (Eh,El) bf16 hi/lo; z -> (resH,resL); W1/W2 -> transposed bf16 ----
__global__ __launch_bounds__(256) void conv_all_kernel(const float* __restrict__ E,
                                                       const float* __restrict__ z,
                                                       const float* __restrict__ W1,
                                                       const float* __restrict__ W2,
                                                       unsigned short* __restrict__ Eh,
                                                       unsigned short* __restrict__ El,
                                                       unsigned short* __restrict__ resH,
                                                       unsigned short* __restrict__ resL,
                                                       unsigned short* __restrict__ w1t,
                                                       unsigned short* __restrict__ w2t) {
    int i = blockIdx.x * 256 + threadIdx.x;
    if (i < 5242880) {
        float f = E[i];
        unsigned short h = f2bf(f);
        Eh[i] = h; El[i] = f2bf(f - bf2f(h));
    } else if (i < 9437184) {
        int j = i - 5242880;
        float f = z[j];
        unsigned short h = f2bf(f);
        resH[j] = h; resL[j] = f2bf(f - bf2f(h));
    } else if (i < 9502720) {
        int j = i - 9437184;
        int n = j >> 8, k = j & 255;
        w1t[j] = f2bf(W1[k * 256 + n]);
    } else {
        int j = i - 9502720;
        int n = j >> 8, k = j & 255;
        w2t[j] = f2bf(W2[k * 1024 + n]);
    }
}

// ---- MFMA screening: 128 tokens x 128 codes per block; hi/lo bf16 split (3 MFMAs) ----
__global__ __launch_bounds__(256) void vq_screen(const unsigned short* __restrict__ resH,
                                                 const unsigned short* __restrict__ resL,
                                                 const unsigned short* __restrict__ Ehi,
                                                 const unsigned short* __restrict__ Eli,
                                                 const float* __restrict__ sseEi,
                                                 int2* __restrict__ gSlots,
                                                 int* __restrict__ gCnt) {
    __shared__ unsigned short sAh[128 * 40], sAl[128 * 40];
    __shared__ unsigned short sBh[128 * 40], sBl[128 * 40];
    __shared__ float sC[128];
    __shared__ int   lCnt[128];
    __shared__ int2  lSlot[128][4];
    const int tid = threadIdx.x;
    const int wv = tid >> 6, lane = tid & 63;
    const int l15 = lane & 15, qd = lane >> 4;
    const int tile = blockIdx.x >> 4, slice = blockIdx.x & 15;
    const int t0 = tile * 128, c0 = slice * 128;

    if (tid < 128) { lCnt[tid] = 0; sC[tid] = sseEi[c0 + tid]; }
    {
        int2 inf; inf.x = 0x7F800000; inf.y = 0;
        ((int2*)lSlot)[tid] = inf; ((int2*)lSlot)[tid + 256] = inf;
    }

    f32x4 acc[2][8];
    #pragma unroll
    for (int m = 0; m < 2; ++m)
        #pragma unroll
        for (int n = 0; n < 8; ++n) acc[m][n] = (f32x4){0.f, 0.f, 0.f, 0.f};

    const int r0 = tid >> 2, c0c = tid & 3;
    const int r1 = (tid + 256) >> 2, c1c = tid & 3;
    for (int kc = 0; kc < 8; ++kc) {
        const int db = kc * 32;
        __syncthreads();
        *(uint4*)(sAh + r0 * 40 + c0c * 8) = *(const uint4*)(resH + (size_t)(t0 + r0) * 256 + db + c0c * 8);
        *(uint4*)(sAh + r1 * 40 + c1c * 8) = *(const uint4*)(resH + (size_t)(t0 + r1) * 256 + db + c1c * 8);
        *(uint4*)(sAl + r0 * 40 + c0c * 8) = *(const uint4*)(resL + (size_t)(t0 + r0) * 256 + db + c0c * 8);
        *(uint4*)(sAl + r1 * 40 + c1c * 8) = *(const uint4*)(resL + (size_t)(t0 + r1) * 256 + db + c1c * 8);
        *(uint4*)(sBh + r0 * 40 + c0c * 8) = *(const uint4*)(Ehi  + (size_t)(c0 + r0) * 256 + db + c0c * 8);
        *(uint4*)(sBh + r1 * 40 + c1c * 8) = *(const uint4*)(Ehi  + (size_t)(c0 + r1) * 256 + db + c1c * 8);
        *(uint4*)(sBl + r0 * 40 + c0c * 8) = *(const uint4*)(Eli  + (size_t)(c0 + r0) * 256 + db + c0c * 8);
        *(uint4*)(sBl + r1 * 40 + c1c * 8) = *(const uint4*)(Eli  + (size_t)(c0 + r1) * 256 + db + c1c * 8);
        __syncthreads();

        short8 ah[2], al[2];
        #pragma unroll
        for (int m = 0; m < 2; ++m) {
            int off = (wv * 32 + m * 16 + l15) * 40 + qd * 8;
            ah[m] = *(const short8*)(sAh + off);
            al[m] = *(const short8*)(sAl + off);
        }
        #pragma unroll
        for (int n = 0; n < 8; ++n) {
            int off = (n * 16 + l15) * 40 + qd * 8;
            short8 bh = *(const short8*)(sBh + off);
            short8 bl = *(const short8*)(sBl + off);
            #pragma unroll
            for (int m = 0; m < 2; ++m) {
                acc[m][n] = __builtin_amdgcn_mfma_f32_16x16x32_bf16(al[m], bh, acc[m][n], 0, 0, 0);
                acc[m][n] = __builtin_amdgcn_mfma_f32_16x16x32_bf16(ah[m], bl, acc[m][n], 0, 0, 0);
                acc[m][n] = __builtin_amdgcn_mfma_f32_16x16x32_bf16(ah[m], bh, acc[m][n], 0, 0, 0);
            }
        }
    }

    #pragma unroll
    for (int m = 0; m < 2; ++m)
        #pragma unroll
        for (int n = 0; n < 8; ++n) {
            float Cv = sC[n * 16 + l15];
            #pragma unroll
            for (int r = 0; r < 4; ++r) acc[m][n][r] = fmaf(-2.f, acc[m][n][r], Cv);
        }
    float tmin[2][4];
    #pragma unroll
    for (int m = 0; m < 2; ++m)
        #pragma unroll
        for (int r = 0; r < 4; ++r) {
            float v = acc[m][0][r];
            #pragma unroll
            for (int n = 1; n < 8; ++n) v = fminf(v, acc[m][n][r]);
            v = fminf(v, __shfl_xor(v, 1, 64));
            v = fminf(v, __shfl_xor(v, 2, 64));
            v = fminf(v, __shfl_xor(v, 4, 64));
            v = fminf(v, __shfl_xor(v, 8, 64));
            tmin[m][r] = v;
        }
    #pragma unroll
    for (int m = 0; m < 2; ++m)
        #pragma unroll
        for (int r = 0; r < 4; ++r) {
            int tloc = wv * 32 + m * 16 + qd * 4 + r;
            float thr = tmin[m][r] + MARGIN;
            #pragma unroll
            for (int n = 0; n < 8; ++n) {
                float sv = acc[m][n][r];
                if (sv <= thr) {
                    int pos = atomicAdd(&lCnt[tloc], 1);
                    if (pos < 4) {
                        int2 e; e.x = __float_as_int(sv); e.y = c0 + n * 16 + l15;
                        lSlot[tloc][pos] = e;
                    }
                }
            }
        }
    __syncthreads();
    {
        int tloc = tid >> 1, half = tid & 1;
        size_t base = (size_t)(t0 + tloc) * 64 + slice * 4 + half * 2;
        gSlots[base]     = lSlot[tloc][half * 2];
        gSlots[base + 1] = lSlot[tloc][half * 2 + 1];
        if (!half) gCnt[(t0 + tloc) * 16 + slice] = lCnt[tloc];
    }
}

// ---- exact np chain for one (token,code): sequential ascending-k f32 FMA ----
static __device__ __forceinline__ float np_chain(const float* __restrict__ sRow,
                                                 const float* __restrict__ Ei,
                                                 int cc, float A, float C) {
    const float4* e = (const float4*)(Ei + (size_t)cc * DDIM);
    float a = 0.f;
    #pragma unroll 8
    for (int k = 0; k < 64; ++k) {
        float4 ev = e[k];
        const float4 rv = *(const float4*)(sRow + k * 4);
        a = fmaf(rv.x, ev.x, a); a = fmaf(rv.y, ev.y, a);
        a = fmaf(rv.z, ev.z, a); a = fmaf(rv.w, ev.w, a);
    }
    return __fadd_rn(fmaf(-2.f, a, A), C);
}

// ---- batched per-token finalize: 256 blocks, wave = 16 tokens in 4 batches of 4 ----
// All independent loads per batch issued up front (slots, res rows, zq rows, counts),
// then winner-reduce, then 4 concurrent Ei gathers, then exact chain + stores + norms.
__global__ __launch_bounds__(256) void vq_post(const float* __restrict__ resSrc,
                                               const float* __restrict__ Ei,
                                               const float* __restrict__ sseEi,
                                               float* __restrict__ res,
                                               float* __restrict__ zq,
                                               float* __restrict__ codes,
                                               float* __restrict__ lossPart,
                                               float* __restrict__ normA,
                                               unsigned short* __restrict__ resHp,
                                               unsigned short* __restrict__ resLp,
                                               unsigned short* __restrict__ zqb,
                                               const int2* __restrict__ gSlots,
                                               const int* __restrict__ gCnt,
                                               int iter) {
    __shared__ float sScr[4][4][256];     // [wave][token-in-batch][dim]
    const int tid = threadIdx.x;
    const int wv = tid >> 6, lane = tid & 63;
    const int g = lane >> 4, l15 = lane & 15;
    const int tw0 = blockIdx.x * 64 + wv * 16;
    float lsum = 0.f;

    for (int b = 0; b < 4; ++b) {
        const int tb = tw0 + b * 4;
        int2 sl[4]; float4 r4[4]; int cnt4[4]; float4 zq4[4];
        #pragma unroll
        for (int j = 0; j < 4; ++j) sl[j] = gSlots[(size_t)(tb + j) * 64 + lane];
        #pragma unroll
        for (int j = 0; j < 4; ++j)
            r4[j] = *(const float4*)(resSrc + (size_t)(tb + j) * DDIM + lane * 4);
        #pragma unroll
        for (int j = 0; j < 4; ++j) cnt4[j] = (lane < 16) ? gCnt[(tb + j) * 16 + lane] : 0;
        if (iter > 0) {
            #pragma unroll
            for (int j = 0; j < 4; ++j)
                zq4[j] = *(const float4*)(zq + (size_t)(tb + j) * DDIM + lane * 4);
        }

        int winner[4];
        #pragma unroll
        for (int j = 0; j < 4; ++j) {
            float sv = __int_as_float(sl[j].x);
            float gm = sv;
            #pragma unroll
            for (int o = 32; o >= 1; o >>= 1) gm = fminf(gm, __shfl_xor(gm, o, 64));
            const bool active = (sv <= gm + MARGIN);
            unsigned long long bal = __ballot(active ? 1 : 0);
            const bool ovf = __any(cnt4[j] > 4);
            if (!ovf && __popcll(bal) == 1) {
                winner[j] = __shfl(sl[j].y, __ffsll(bal) - 1, 64);
            } else {                         // rare, wave-uniform slow path
                *(float4*)(&sScr[wv][j][lane * 4]) = r4[j];
                const float A = normA[tb + j];
                unsigned long long best = ~0ULL;
                if (ovf) {
                    for (int cc = lane; cc < KCB; cc += 64) {
                        float s = np_chain(sScr[wv][j], Ei, cc, A, sseEi[cc]);
                        unsigned long long key =
                            ((unsigned long long)__float_as_uint(s) << 32) | (unsigned)cc;
                        if (key < best) best = key;
                    }
                } else if (active) {
                    float s = np_chain(sScr[wv][j], Ei, sl[j].y, A, sseEi[sl[j].y]);
                    best = ((unsigned long long)__float_as_uint(s) << 32) | (unsigned)sl[j].y;
                }
                #pragma unroll
                for (int o = 32; o >= 1; o >>= 1) {
                    unsigned long long ot = __shfl_xor(best, o, 64);
                    if (ot < best) best = ot;
                }
                winner[j] = (int)(unsigned)(best & 0xFFFFFFFFu);
            }
        }
        #pragma unroll
        for (int j = 0; j < 4; ++j)
            if (lane == j) codes[(size_t)(tb + j) * NCB + iter] = (float)winner[j];

        float4 q4[4];
        #pragma unroll
        for (int j = 0; j < 4; ++j)
            q4[j] = *(const float4*)(Ei + (size_t)winner[j] * DDIM + lane * 4);

        #pragma unroll
        for (int j = 0; j < 4; ++j) {
            const size_t go = (size_t)(tb + j) * DDIM + lane * 4;
            float4 rn4, zqi4;
            float tqx = q4[j].x - r4[j].x; zqi4.x = r4[j].x + tqx; rn4.x = r4[j].x - zqi4.x;
            float tqy = q4[j].y - r4[j].y; zqi4.y = r4[j].y + tqy; rn4.y = r4[j].y - zqi4.y;
            float tqz = q4[j].z - r4[j].z; zqi4.z = r4[j].z + tqz; rn4.z = r4[j].z - zqi4.z;
            float tqw = q4[j].w - r4[j].w; zqi4.w = r4[j].w + tqw; rn4.w = r4[j].w - zqi4.w;
            lsum = fmaf(tqx, tqx, lsum); lsum = fmaf(tqy, tqy, lsum);
            lsum = fmaf(tqz, tqz, lsum); lsum = fmaf(tqw, tqw, lsum);
            *(float4*)(res + go) = rn4;
            {
                unsigned short hx = f2bf(rn4.x), hy = f2bf(rn4.y),
                               hz = f2bf(rn4.z), hw = f2bf(rn4.w);
                unsigned short h[4] = { hx, hy, hz, hw };
                unsigned short lo[4] = { f2bf(rn4.x - bf2f(hx)), f2bf(rn4.y - bf2f(hy)),
                                         f2bf(rn4.z - bf2f(hz)), f2bf(rn4.w - bf2f(hw)) };
                *(ushort4*)(resHp + go) = *(ushort4*)h;
                *(ushort4*)(resLp + go) = *(ushort4*)lo;
            }
            if (iter == 0) {
                *(float4*)(zq + go) = zqi4;
                unsigned short u[4] = { f2bf(zqi4.x), f2bf(zqi4.y), f2bf(zqi4.z), f2bf(zqi4.w) };
                *(ushort4*)(zqb + go) = *(ushort4*)u;
            } else {
                zq4[j].x += zqi4.x; zq4[j].y += zqi4.y;
                zq4[j].z += zqi4.z; zq4[j].w += zqi4.w;
                *(float4*)(zq + go) = zq4[j];
            }
            *(float4*)(&sScr[wv][j][lane * 4]) = rn4;
        }
        // np-exact norms: 16-lane group g handles token tb+g (4 tokens in parallel)
        {
            const float* a = &sScr[wv][g][((l15 >> 3) << 7) + (l15 & 7)];
            float v = a[0];
            float r = __fmul_rn(v, v);
            #pragma unroll
            for (int k = 1; k < 16; ++k) { v = a[k * 8]; r = __fadd_rn(r, __fmul_rn(v, v)); }
            r = __fadd_rn(r, __shfl_xor(r, 1, 64));
            r = __fadd_rn(r, __shfl_xor(r, 2, 64));
            r = __fadd_rn(r, __shfl_xor(r, 4, 64));
            r = __fadd_rn(r, __shfl_xor(r, 8, 64));
            if (l15 == 0) normA[tb + g] = r;
        }
    }
    #pragma unroll
    for (int o = 32; o >= 1; o >>= 1) lsum += __shfl_xor(lsum, o, 64);
    if (lane == 0) lossPart[blockIdx.x * 4 + wv] = lsum;
}

// ---- vq loss finalize (1024 wave partials) ----
__global__ __launch_bounds__(256) void loss_final(const float* __restrict__ lossPart,
                                                  float* __restrict__ vql) {
    __shared__ float sRed[4];
    float s = 0.f;
    for (int i = threadIdx.x; i < 1024; i += 256) s += lossPart[i];
    #pragma unroll
    for (int o = 32; o >= 1; o >>= 1) s += __shfl_xor(s, o, 64);
    if ((threadIdx.x & 63) == 0) sRed[threadIdx.x >> 6] = s;
    __syncthreads();
    if (threadIdx.x == 0)
        vql[0] = (sRed[0] + sRed[1] + sRed[2] + sRed[3]) * (1.25f / 4194304.f);
}

// ---- semantic head, bf16 MFMA ----
__global__ __launch_bounds__(256) void semantic_mfma(const unsigned short* __restrict__ zqb,
                                                     const float* __restrict__ tgt,
                                                     const unsigned short* __restrict__ w1t,
                                                     const float* __restrict__ b1,
                                                     const unsigned short* __restrict__ w2t,
                                                     const float* __restrict__ b2,
                                                     float* __restrict__ semLoss) {
    __shared__ unsigned short sZ[32 * 264];
    __shared__ unsigned short sH[32 * 264];
    __shared__ float sRed[4];
    const int tid = threadIdx.x;
    const int wv = tid >> 6, lane = tid & 63;
    const int l15 = lane & 15, qd = lane >> 4;
    const int tb = blockIdx.x * 32;

    {
        int row = tid >> 3, seg = tid & 7;
        const uint4* src = (const uint4*)(zqb + (size_t)(tb + row) * 256);
        uint4* dst = (uint4*)(&sZ[row * 264]);
        #pragma unroll
        for (int p = 0; p < 4; ++p) dst[seg * 4 + p] = src[seg * 4 + p];
    }
    __syncthreads();

    short8 az[8][2];
    #pragma unroll
    for (int kc = 0; kc < 8; ++kc)
        #pragma unroll
        for (int m = 0; m < 2; ++m)
            az[kc][m] = *(const short8*)(&sZ[(16 * m + l15) * 264 + kc * 32 + qd * 8]);

    #pragma unroll
    for (int nt4 = 0; nt4 < 4; ++nt4) {
        const int nt = wv * 4 + nt4;
        f32x4 acc0 = {0.f,0.f,0.f,0.f}, acc1 = {0.f,0.f,0.f,0.f};
        const unsigned short* bb = w1t + (size_t)(16 * nt + l15) * 256 + qd * 8;
        #pragma unroll
        for (int kc = 0; kc < 8; ++kc) {
            short8 b = *(const short8*)(bb + kc * 32);
            acc0 = __builtin_amdgcn_mfma_f32_16x16x32_bf16(az[kc][0], b, acc0, 0, 0, 0);
            acc1 = __builtin_amdgcn_mfma_f32_16x16x32_bf16(az[kc][1], b, acc1, 0, 0, 0);
        }
        const float b1v = b1[16 * nt + l15];
        #pragma unroll
        for (int r = 0; r < 4; ++r) {
            float x0 = acc0[r] + b1v;
            float x1 = acc1[r] + b1v;
            sH[(4 * qd + r) * 264 + 16 * nt + l15]      = f2bf(0.5f * x0 * (1.f + erff(x0 * 0.70710678f)));
            sH[(16 + 4 * qd + r) * 264 + 16 * nt + l15] = f2bf(0.5f * x1 * (1.f + erff(x1 * 0.70710678f)));
        }
    }
    __syncthreads();

    short8 ah[8][2];
    #pragma unroll
    for (int kc = 0; kc < 8; ++kc)
        #pragma unroll
        for (int m = 0; m < 2; ++m)
            ah[kc][m] = *(const short8*)(&sH[(16 * m + l15) * 264 + kc * 32 + qd * 8]);

    float lsum = 0.f;
    for (int t = 0; t < 16; ++t) {
        const int nt = wv * 16 + t;
        f32x4 acc0 = {0.f,0.f,0.f,0.f}, acc1 = {0.f,0.f,0.f,0.f};
        const unsigned short* bb = w2t + (size_t)(16 * nt + l15) * 256 + qd * 8;
        #pragma unroll
        for (int kc = 0; kc < 8; ++kc) {
            short8 b = *(const short8*)(bb + kc * 32);
            acc0 = __builtin_amdgcn_mfma_f32_16x16x32_bf16(ah[kc][0], b, acc0, 0, 0, 0);
            acc1 = __builtin_amdgcn_mfma_f32_16x16x32_bf16(ah[kc][1], b, acc1, 0, 0, 0);
        }
        const int n = 16 * nt + l15;
        const float b2v = b2[n];
        #pragma unroll
        for (int r = 0; r < 4; ++r) {
            float dv0 = (acc0[r] + b2v) - tgt[(size_t)(tb + 4 * qd + r) * 1024 + n];
            float dv1 = (acc1[r] + b2v) - tgt[(size_t)(tb + 16 + 4 * qd + r) * 1024 + n];
            lsum = fmaf(dv0, dv0, lsum);
            lsum = fmaf(dv1, dv1, lsum);
        }
    }
    #pragma unroll
    for (int o = 32; o >= 1; o >>= 1) lsum += __shfl_xor(lsum, o, 64);
    if (lane == 0) sRed[wv] = lsum;
    __syncthreads();
    if (tid == 0)
        atomicAdd(semLoss, (sRed[0] + sRed[1] + sRed[2] + sRed[3]) * (1.0f / 16777216.f));
}

extern "C" void kernel_launch(void* const* d_in, const int* in_sizes, int n_in,
                              void* d_out, int out_size, void* d_ws, size_t ws_size,
                              hipStream_t stream) {
    const float* z   = (const float*)d_in[0];
    const float* tgt = (const float*)d_in[1];
    const float* E   = (const float*)d_in[2];
    const float* W1  = (const float*)d_in[3];
    const float* b1  = (const float*)d_in[4];
    const float* W2  = (const float*)d_in[5];
    const float* b2  = (const float*)d_in[6];

    float* out   = (float*)d_out;
    float* zq    = out;
    float* codes = out + (size_t)NTOK * DDIM;
    float* vql   = codes + (size_t)NTOK * NCB;       // [vq_loss, semantic_loss]

    char* w = (char*)d_ws;
    float*          res   = (float*)(w);                         // 16 MiB
    unsigned short* resH  = (unsigned short*)(w + 16777216);     // 8 MiB
    unsigned short* resL  = (unsigned short*)(w + 25165824);     // 8 MiB
    unsigned short* Eh    = (unsigned short*)(w + 33554432);     // 10 MiB
    unsigned short* El    = (unsigned short*)(w + 44040192);     // 10 MiB
    unsigned short* zqb   = (unsigned short*)(w + 54525952);     // 8 MiB
    int2*           gSlots= (int2*)(w + 62914560);               // 8 MiB
    int*            gCnt  = (int*)(w + 71303168);                // 1 MiB
    float*          sseE  = (float*)(w + 72351744);              // 80 KiB
    float*          normA = (float*)(w + 72482816);              // 64 KiB
    float*          lossPart=(float*)(w + 72613888);             // 4 KiB
    unsigned short* w1t   = (unsigned short*)(w + 72744960);     // 128 KiB
    unsigned short* w2t   = (unsigned short*)(w + 72876032);     // 512 KiB

    hipMemsetAsync(vql, 0, 2 * sizeof(float), stream);
    norms_all_kernel<<<9216, 256, 0, stream>>>(E, z, sseE, normA);
    conv_all_kernel<<<38144, 256, 0, stream>>>(E, z, W1, W2, Eh, El, resH, resL, w1t, w2t);
    for (int it = 0; it < NCB; ++it) {
        const float*          Ei    = E  + (size_t)it * KCB * DDIM;
        const unsigned short* Ehi   = Eh + (size_t)it * KCB * DDIM;
        const unsigned short* Eli   = El + (size_t)it * KCB * DDIM;
        const float*          sseEi = sseE + (size_t)it * KCB;
        const float* resSrc = (it == 0) ? z : res;
        vq_screen<<<2048, 256, 0, stream>>>(resH, resL, Ehi, Eli, sseEi, gSlots, gCnt);
        vq_post<<<256, 256, 0, stream>>>(resSrc, Ei, sseEi, res, zq, codes, lossPart,
                                         normA, resH, resL, zqb, gSlots, gCnt, it);
        if (it == 0)
            semantic_mfma<<<512, 256, 0, stream>>>(zqb, tgt, w1t, b1, w2t, b2, vql + 1);
    }
    loss_final<<<1, 256, 0, stream>>>(lossPart, vql);
}

// Round 7
// 1404.335 us; speedup vs baseline: 2.0544x; 1.1853x over previous
//
#include <hip/hip_runtime.h>
#include <float.h>
#include <math.h>

#define NTOK 16384
#define KCB  2048
#define DDIM 256
#define NCB  10
#define MARGIN 1.0e-4f

typedef __attribute__((ext_vector_type(8))) short  short8;
typedef __attribute__((ext_vector_type(4))) float  f32x4;

static __device__ __forceinline__ unsigned short f2bf(float f) {
    unsigned int b = __float_as_uint(f);
    unsigned int r = b + 0x7FFFu + ((b >> 16) & 1u);   // RNE
    return (unsigned short)(r >> 16);
}
static __device__ __forceinline__ float bf2f(unsigned short h) {
    return __uint_as_float((unsigned int)h << 16);
}

// ---- np-bit-exact pairwise sum of squares (rows of 256): E rows + z rows ----
__global__ __launch_bounds__(256) void norms_all_kernel(const float* __restrict__ E,
                                                        const float* __restrict__ z,
                                                        float* __restrict__ sseE,
                                                        float* __restrict__ normA) {
    const int gw   = (blockIdx.x * 256 + threadIdx.x) >> 6;
    const int lane = threadIdx.x & 63;
    const int row  = gw * 4 + (lane >> 4);
    const int l    = lane & 15;
    const float* src = nullptr; float* dst = nullptr;
    if (row < NCB * KCB)             { src = E + (size_t)row * DDIM;               dst = sseE + row; }
    else if (row < NCB * KCB + NTOK) { src = z + (size_t)(row - NCB * KCB) * DDIM; dst = normA + (row - NCB * KCB); }
    float r = 0.f;
    if (src) {
        const float* a = src + ((l >> 3) << 7) + (l & 7);
        float v = a[0];
        r = __fmul_rn(v, v);
        #pragma unroll
        for (int k = 1; k < 16; ++k) { v = a[k * 8]; r = __fadd_rn(r, __fmul_rn(v, v)); }
    }
    r = __fadd_rn(r, __shfl_xor(r, 1, 64));
    r = __fadd_rn(r, __shfl_xor(r, 2, 64));
    r = __fadd_rn(r, __shfl_xor(r, 4, 64));
    r = __fadd_rn(r, __shfl_xor(r, 8, 64));
    if (src && l == 0) *dst = r;
}

// ---- convert: E -> (Eh,El) bf16 hi/lo; z -> (resH,resL); W1/W2 -> transposed bf16 ----
__global__ __launch_bounds__(256) void conv_all_kernel(const float* __restrict__ E,
                                                       const float* __restrict__ z,
                                                       const float* __restrict__ W1,
                                                       const float* __restrict__ W2,
                                                       unsigned short* __restrict__ Eh,
                                                       unsigned short* __restrict__ El,
                                                       unsigned short* __restrict__ resH,
                                                       unsigned short* __restrict__ resL,
                                                       unsigned short* __restrict__ w1t,
                                                       unsigned short* __restrict__ w2t) {
    int i = blockIdx.x * 256 + threadIdx.x;
    if (i < 5242880) {
        float f = E[i];
        unsigned short h = f2bf(f);
        Eh[i] = h; El[i] = f2bf(f - bf2f(h));
    } else if (i < 9437184) {
        int j = i - 5242880;
        float f = z[j];
        unsigned short h = f2bf(f);
        resH[j] = h; resL[j] = f2bf(f - bf2f(h));
    } else if (i < 9502720) {
        int j = i - 9437184;
        int n = j >> 8, k = j & 255;
        w1t[j] = f2bf(W1[k * 256 + n]);
    } else {
        int j = i - 9502720;
        int n = j >> 8, k = j & 255;
        w2t[j] = f2bf(W2[k * 1024 + n]);
    }
}

// ---- MFMA screening: 128 tokens x 128 codes per block; hi/lo bf16 split (3 MFMAs) ----
// Outputs per (token,slice): true slice min (gMin), candidate slots within MARGIN, count.
__global__ __launch_bounds__(256) void vq_screen(const unsigned short* __restrict__ resH,
                                                 const unsigned short* __restrict__ resL,
                                                 const unsigned short* __restrict__ Ehi,
                                                 const unsigned short* __restrict__ Eli,
                                                 const float* __restrict__ sseEi,
                                                 int2* __restrict__ gSlots,
                                                 int* __restrict__ gCnt,
                                                 float* __restrict__ gMin) {
    __shared__ unsigned short sAh[128 * 40], sAl[128 * 40];
    __shared__ unsigned short sBh[128 * 40], sBl[128 * 40];
    __shared__ float sC[128];
    __shared__ int   lCnt[128];
    __shared__ int2  lSlot[128][4];
    const int tid = threadIdx.x;
    const int wv = tid >> 6, lane = tid & 63;
    const int l15 = lane & 15, qd = lane >> 4;
    const int tile = blockIdx.x >> 4, slice = blockIdx.x & 15;
    const int t0 = tile * 128, c0 = slice * 128;

    if (tid < 128) { lCnt[tid] = 0; sC[tid] = sseEi[c0 + tid]; }
    {
        int2 inf; inf.x = 0x7F800000; inf.y = 0;
        ((int2*)lSlot)[tid] = inf; ((int2*)lSlot)[tid + 256] = inf;
    }

    f32x4 acc[2][8];
    #pragma unroll
    for (int m = 0; m < 2; ++m)
        #pragma unroll
        for (int n = 0; n < 8; ++n) acc[m][n] = (f32x4){0.f, 0.f, 0.f, 0.f};

    const int r0 = tid >> 2, c0c = tid & 3;
    const int r1 = (tid + 256) >> 2, c1c = tid & 3;
    for (int kc = 0; kc < 8; ++kc) {
        const int db = kc * 32;
        __syncthreads();
        *(uint4*)(sAh + r0 * 40 + c0c * 8) = *(const uint4*)(resH + (size_t)(t0 + r0) * 256 + db + c0c * 8);
        *(uint4*)(sAh + r1 * 40 + c1c * 8) = *(const uint4*)(resH + (size_t)(t0 + r1) * 256 + db + c1c * 8);
        *(uint4*)(sAl + r0 * 40 + c0c * 8) = *(const uint4*)(resL + (size_t)(t0 + r0) * 256 + db + c0c * 8);
        *(uint4*)(sAl + r1 * 40 + c1c * 8) = *(const uint4*)(resL + (size_t)(t0 + r1) * 256 + db + c1c * 8);
        *(uint4*)(sBh + r0 * 40 + c0c * 8) = *(const uint4*)(Ehi  + (size_t)(c0 + r0) * 256 + db + c0c * 8);
        *(uint4*)(sBh + r1 * 40 + c1c * 8) = *(const uint4*)(Ehi  + (size_t)(c0 + r1) * 256 + db + c1c * 8);
        *(uint4*)(sBl + r0 * 40 + c0c * 8) = *(const uint4*)(Eli  + (size_t)(c0 + r0) * 256 + db + c0c * 8);
        *(uint4*)(sBl + r1 * 40 + c1c * 8) = *(const uint4*)(Eli  + (size_t)(c0 + r1) * 256 + db + c1c * 8);
        __syncthreads();

        short8 ah[2], al[2];
        #pragma unroll
        for (int m = 0; m < 2; ++m) {
            int off = (wv * 32 + m * 16 + l15) * 40 + qd * 8;
            ah[m] = *(const short8*)(sAh + off);
            al[m] = *(const short8*)(sAl + off);
        }
        #pragma unroll
        for (int n = 0; n < 8; ++n) {
            int off = (n * 16 + l15) * 40 + qd * 8;
            short8 bh = *(const short8*)(sBh + off);
            short8 bl = *(const short8*)(sBl + off);
            #pragma unroll
            for (int m = 0; m < 2; ++m) {
                acc[m][n] = __builtin_amdgcn_mfma_f32_16x16x32_bf16(al[m], bh, acc[m][n], 0, 0, 0);
                acc[m][n] = __builtin_amdgcn_mfma_f32_16x16x32_bf16(ah[m], bl, acc[m][n], 0, 0, 0);
                acc[m][n] = __builtin_amdgcn_mfma_f32_16x16x32_bf16(ah[m], bh, acc[m][n], 0, 0, 0);
            }
        }
    }

    #pragma unroll
    for (int m = 0; m < 2; ++m)
        #pragma unroll
        for (int n = 0; n < 8; ++n) {
            float Cv = sC[n * 16 + l15];
            #pragma unroll
            for (int r = 0; r < 4; ++r) acc[m][n][r] = fmaf(-2.f, acc[m][n][r], Cv);
        }
    #pragma unroll
    for (int m = 0; m < 2; ++m)
        #pragma unroll
        for (int r = 0; r < 4; ++r) {
            float v = acc[m][0][r];
            #pragma unroll
            for (int n = 1; n < 8; ++n) v = fminf(v, acc[m][n][r]);
            v = fminf(v, __shfl_xor(v, 1, 64));
            v = fminf(v, __shfl_xor(v, 2, 64));
            v = fminf(v, __shfl_xor(v, 4, 64));
            v = fminf(v, __shfl_xor(v, 8, 64));
            int tloc = wv * 32 + m * 16 + qd * 4 + r;
            if (l15 == 0) gMin[(t0 + tloc) * 16 + slice] = v;   // true slice min
            float thr = v + MARGIN;
            #pragma unroll
            for (int n = 0; n < 8; ++n) {
                float sv = acc[m][n][r];
                if (sv <= thr) {
                    int pos = atomicAdd(&lCnt[tloc], 1);
                    if (pos < 4) {
                        int2 e; e.x = __float_as_int(sv); e.y = c0 + n * 16 + l15;
                        lSlot[tloc][pos] = e;
                    }
                }
            }
        }
    __syncthreads();
    {
        int tloc = tid >> 1, half = tid & 1;
        size_t base = (size_t)(t0 + tloc) * 64 + slice * 4 + half * 2;
        gSlots[base]     = lSlot[tloc][half * 2];
        gSlots[base + 1] = lSlot[tloc][half * 2 + 1];
        if (!half) gCnt[(t0 + tloc) * 16 + slice] = lCnt[tloc];
    }
}

// ---- exact np chain (per-lane, row from LDS copy of res) ----
static __device__ __forceinline__ float np_chain(const float* __restrict__ sRow,
                                                 const float* __restrict__ Ei,
                                                 int cc, float A, float C) {
    const float4* e = (const float4*)(Ei + (size_t)cc * DDIM);
    float a = 0.f;
    #pragma unroll 8
    for (int k = 0; k < 64; ++k) {
        float4 ev = e[k];
        const float4 rv = *(const float4*)(sRow + k * 4);
        a = fmaf(rv.x, ev.x, a); a = fmaf(rv.y, ev.y, a);
        a = fmaf(rv.z, ev.z, a); a = fmaf(rv.w, ev.w, a);
    }
    return __fadd_rn(fmaf(-2.f, a, A), C);
}

// ---- finalize: 1024 blocks x 4 waves x 4 tokens/wave ----
__global__ __launch_bounds__(256) void vq_post(const float* __restrict__ resSrc,
                                               const float* __restrict__ Ei,
                                               const float* __restrict__ sseEi,
                                               float* __restrict__ res,
                                               float* __restrict__ zq,
                                               float* __restrict__ codes,
                                               float* __restrict__ lossPart,
                                               float* __restrict__ normA,
                                               unsigned short* __restrict__ resHp,
                                               unsigned short* __restrict__ resLp,
                                               unsigned short* __restrict__ zqb,
                                               const int2* __restrict__ gSlots,
                                               const int* __restrict__ gCnt,
                                               const float* __restrict__ gMin,
                                               int iter) {
    __shared__ float sScr[4][4][256];
    const int tid = threadIdx.x;
    const int wv = tid >> 6, lane = tid & 63;
    const int g = lane >> 4, l15 = lane & 15;
    const int tb = blockIdx.x * 16 + wv * 4;
    float lsum = 0.f;

    // phase 1: all independent loads
    int2 sl[4]; float4 r4[4]; int cnt4[4]; float smin4[4]; float4 zq4[4]; float A4[4];
    #pragma unroll
    for (int j = 0; j < 4; ++j) sl[j] = gSlots[(size_t)(tb + j) * 64 + lane];
    #pragma unroll
    for (int j = 0; j < 4; ++j)
        r4[j] = *(const float4*)(resSrc + (size_t)(tb + j) * DDIM + lane * 4);
    #pragma unroll
    for (int j = 0; j < 4; ++j) cnt4[j]  = (lane < 16) ? gCnt[(tb + j) * 16 + lane] : 0;
    #pragma unroll
    for (int j = 0; j < 4; ++j) smin4[j] = (lane < 16) ? gMin[(tb + j) * 16 + lane] : FLT_MAX;
    #pragma unroll
    for (int j = 0; j < 4; ++j) A4[j] = normA[tb + j];
    if (iter > 0) {
        #pragma unroll
        for (int j = 0; j < 4; ++j)
            zq4[j] = *(const float4*)(zq + (size_t)(tb + j) * DDIM + lane * 4);
    }

    // phase 2: winners
    int winner[4];
    #pragma unroll
    for (int j = 0; j < 4; ++j) {
        float gm = smin4[j];
        #pragma unroll
        for (int o = 32; o >= 1; o >>= 1) gm = fminf(gm, __shfl_xor(gm, o, 64));
        const float thr = gm + MARGIN;
        float sv = __int_as_float(sl[j].x);
        unsigned long long bal = __ballot((sv <= thr) ? 1 : 0);
        bool ovfRel = __any((lane < 16 && cnt4[j] > 4 && smin4[j] <= thr) ? 1 : 0);
        if (!ovfRel && __popcll(bal) == 1) {
            winner[j] = __shfl(sl[j].y, __ffsll(bal) - 1, 64);
        } else if (!ovfRel) {
            // wave-uniform exact eval of the few candidates (coalesced row load +
            // readlane serial chain; bit-identical to np's sequential FMA chain)
            unsigned long long b = bal;
            unsigned long long best = ~0ULL;
            while (b) {
                int src = __ffsll(b) - 1; b &= b - 1;
                int cc = __shfl(sl[j].y, src, 64);
                float4 ev = *(const float4*)(Ei + (size_t)cc * DDIM + lane * 4);
                float a = 0.f;
                #pragma unroll 16
                for (int k = 0; k < 64; ++k) {
                    float ex = __shfl(ev.x, k, 64), ey = __shfl(ev.y, k, 64);
                    float ez = __shfl(ev.z, k, 64), ew = __shfl(ev.w, k, 64);
                    float rx = __shfl(r4[j].x, k, 64), ry = __shfl(r4[j].y, k, 64);
                    float rz = __shfl(r4[j].z, k, 64), rw = __shfl(r4[j].w, k, 64);
                    a = fmaf(rx, ex, a); a = fmaf(ry, ey, a);
                    a = fmaf(rz, ez, a); a = fmaf(rw, ew, a);
                }
                float s = __fadd_rn(fmaf(-2.f, a, A4[j]), sseEi[cc]);
                unsigned long long key =
                    ((unsigned long long)__float_as_uint(s) << 32) | (unsigned)cc;
                if (key < best) best = key;
            }
            winner[j] = (int)(unsigned)(best & 0xFFFFFFFFu);
        } else {
            // rare (~1 token/iter): full exact rescan
            *(float4*)(&sScr[wv][j][lane * 4]) = r4[j];
            unsigned long long best = ~0ULL;
            for (int cc = lane; cc < KCB; cc += 64) {
                float s = np_chain(sScr[wv][j], Ei, cc, A4[j], sseEi[cc]);
                unsigned long long key =
                    ((unsigned long long)__float_as_uint(s) << 32) | (unsigned)cc;
                if (key < best) best = key;
            }
            #pragma unroll
            for (int o = 32; o >= 1; o >>= 1) {
                unsigned long long ot = __shfl_xor(best, o, 64);
                if (ot < best) best = ot;
            }
            winner[j] = (int)(unsigned)(best & 0xFFFFFFFFu);
        }
    }
    #pragma unroll
    for (int j = 0; j < 4; ++j)
        if (lane == j) codes[(size_t)(tb + j) * NCB + iter] = (float)winner[j];

    // phase 3: concurrent gathers
    float4 q4[4];
    #pragma unroll
    for (int j = 0; j < 4; ++j)
        q4[j] = *(const float4*)(Ei + (size_t)winner[j] * DDIM + lane * 4);

    // phase 4: exact chain update + stores
    #pragma unroll
    for (int j = 0; j < 4; ++j) {
        const size_t go = (size_t)(tb + j) * DDIM + lane * 4;
        float4 rn4, zqi4;
        float tqx = q4[j].x - r4[j].x; zqi4.x = r4[j].x + tqx; rn4.x = r4[j].x - zqi4.x;
        float tqy = q4[j].y - r4[j].y; zqi4.y = r4[j].y + tqy; rn4.y = r4[j].y - zqi4.y;
        float tqz = q4[j].z - r4[j].z; zqi4.z = r4[j].z + tqz; rn4.z = r4[j].z - zqi4.z;
        float tqw = q4[j].w - r4[j].w; zqi4.w = r4[j].w + tqw; rn4.w = r4[j].w - zqi4.w;
        lsum = fmaf(tqx, tqx, lsum); lsum = fmaf(tqy, tqy, lsum);
        lsum = fmaf(tqz, tqz, lsum); lsum = fmaf(tqw, tqw, lsum);
        *(float4*)(res + go) = rn4;
        {
            unsigned short hx = f2bf(rn4.x), hy = f2bf(rn4.y),
                           hz = f2bf(rn4.z), hw = f2bf(rn4.w);
            unsigned short h[4] = { hx, hy, hz, hw };
            unsigned short lo[4] = { f2bf(rn4.x - bf2f(hx)), f2bf(rn4.y - bf2f(hy)),
                                     f2bf(rn4.z - bf2f(hz)), f2bf(rn4.w - bf2f(hw)) };
            *(ushort4*)(resHp + go) = *(ushort4*)h;
            *(ushort4*)(resLp + go) = *(ushort4*)lo;
        }
        if (iter == 0) {
            *(float4*)(zq + go) = zqi4;
            unsigned short u[4] = { f2bf(zqi4.x), f2bf(zqi4.y), f2bf(zqi4.z), f2bf(zqi4.w) };
            *(ushort4*)(zqb + go) = *(ushort4*)u;
        } else {
            zq4[j].x += zqi4.x; zq4[j].y += zqi4.y;
            zq4[j].z += zqi4.z; zq4[j].w += zqi4.w;
            *(float4*)(zq + go) = zq4[j];
        }
        *(float4*)(&sScr[wv][j][lane * 4]) = rn4;
    }
    // phase 5: np-exact norms, 4 tokens in parallel (16-lane group g -> token tb+g)
    {
        const float* a = &sScr[wv][g][((l15 >> 3) << 7) + (l15 & 7)];
        float v = a[0];
        float r = __fmul_rn(v, v);
        #pragma unroll
        for (int k = 1; k < 16; ++k) { v = a[k * 8]; r = __fadd_rn(r, __fmul_rn(v, v)); }
        r = __fadd_rn(r, __shfl_xor(r, 1, 64));
        r = __fadd_rn(r, __shfl_xor(r, 2, 64));
        r = __fadd_rn(r, __shfl_xor(r, 4, 64));
        r = __fadd_rn(r, __shfl_xor(r, 8, 64));
        if (l15 == 0) normA[tb + g] = r;
    }
    #pragma unroll
    for (int o = 32; o >= 1; o >>= 1) lsum += __shfl_xor(lsum, o, 64);
    if (lane == 0) lossPart[iter * 4096 + blockIdx.x * 4 + wv] = lsum;
}

// ---- vq loss finalize (10 iters x 4096 wave partials) ----
__global__ __launch_bounds__(256) void loss_final(const float* __restrict__ lossPart,
                                                  float* __restrict__ vql) {
    __shared__ float sRed[4];
    float s = 0.f;
    for (int i = threadIdx.x; i < 40960; i += 256) s += lossPart[i];
    #pragma unroll
    for (int o = 32; o >= 1; o >>= 1) s += __shfl_xor(s, o, 64);
    if ((threadIdx.x & 63) == 0) sRed[threadIdx.x >> 6] = s;
    __syncthreads();
    if (threadIdx.x == 0)
        vql[0] = (sRed[0] + sRed[1] + sRed[2] + sRed[3]) * (1.25f / 4194304.f);
}

// ---- semantic head, bf16 MFMA ----
__global__ __launch_bounds__(256) void semantic_mfma(const unsigned short* __restrict__ zqb,
                                                     const float* __restrict__ tgt,
                                                     const unsigned short* __restrict__ w1t,
                                                     const float* __restrict__ b1,
                                                     const unsigned short* __restrict__ w2t,
                                                     const float* __restrict__ b2,
                                                     float* __restrict__ semLoss) {
    __shared__ unsigned short sZ[32 * 264];
    __shared__ unsigned short sH[32 * 264];
    __shared__ float sRed[4];
    const int tid = threadIdx.x;
    const int wv = tid >> 6, lane = tid & 63;
    const int l15 = lane & 15, qd = lane >> 4;
    const int tb = blockIdx.x * 32;

    {
        int row = tid >> 3, seg = tid & 7;
        const uint4* src = (const uint4*)(zqb + (size_t)(tb + row) * 256);
        uint4* dst = (uint4*)(&sZ[row * 264]);
        #pragma unroll
        for (int p = 0; p < 4; ++p) dst[seg * 4 + p] = src[seg * 4 + p];
    }
    __syncthreads();

    short8 az[8][2];
    #pragma unroll
    for (int kc = 0; kc < 8; ++kc)
        #pragma unroll
        for (int m = 0; m < 2; ++m)
            az[kc][m] = *(const short8*)(&sZ[(16 * m + l15) * 264 + kc * 32 + qd * 8]);

    #pragma unroll
    for (int nt4 = 0; nt4 < 4; ++nt4) {
        const int nt = wv * 4 + nt4;
        f32x4 acc0 = {0.f,0.f,0.f,0.f}, acc1 = {0.f,0.f,0.f,0.f};
        const unsigned short* bb = w1t + (size_t)(16 * nt + l15) * 256 + qd * 8;
        #pragma unroll
        for (int kc = 0; kc < 8; ++kc) {
            short8 b = *(const short8*)(bb + kc * 32);
            acc0 = __builtin_amdgcn_mfma_f32_16x16x32_bf16(az[kc][0], b, acc0, 0, 0, 0);
            acc1 = __builtin_amdgcn_mfma_f32_16x16x32_bf16(az[kc][1], b, acc1, 0, 0, 0);
        }
        const float b1v = b1[16 * nt + l15];
        #pragma unroll
        for (int r = 0; r < 4; ++r) {
            float x0 = acc0[r] + b1v;
            float x1 = acc1[r] + b1v;
            sH[(4 * qd + r) * 264 + 16 * nt + l15]      = f2bf(0.5f * x0 * (1.f + erff(x0 * 0.70710678f)));
            sH[(16 + 4 * qd + r) * 264 + 16 * nt + l15] = f2bf(0.5f * x1 * (1.f + erff(x1 * 0.70710678f)));
        }
    }
    __syncthreads();

    short8 ah[8][2];
    #pragma unroll
    for (int kc = 0; kc < 8; ++kc)
        #pragma unroll
        for (int m = 0; m < 2; ++m)
            ah[kc][m] = *(const short8*)(&sH[(16 * m + l15) * 264 + kc * 32 + qd * 8]);

    float lsum = 0.f;
    for (int t = 0; t < 16; ++t) {
        const int nt = wv * 16 + t;
        f32x4 acc0 = {0.f,0.f,0.f,0.f}, acc1 = {0.f,0.f,0.f,0.f};
        const unsigned short* bb = w2t + (size_t)(16 * nt + l15) * 256 + qd * 8;
        #pragma unroll
        for (int kc = 0; kc < 8; ++kc) {
            short8 b = *(const short8*)(bb + kc * 32);
            acc0 = __builtin_amdgcn_mfma_f32_16x16x32_bf16(ah[kc][0], b, acc0, 0, 0, 0);
            acc1 = __builtin_amdgcn_mfma_f32_16x16x32_bf16(ah[kc][1], b, acc1, 0, 0, 0);
        }
        const int n = 16 * nt + l15;
        const float b2v = b2[n];
        #pragma unroll
        for (int r = 0; r < 4; ++r) {
            float dv0 = (acc0[r] + b2v) - tgt[(size_t)(tb + 4 * qd + r) * 1024 + n];
            float dv1 = (acc1[r] + b2v) - tgt[(size_t)(tb + 16 + 4 * qd + r) * 1024 + n];
            lsum = fmaf(dv0, dv0, lsum);
            lsum = fmaf(dv1, dv1, lsum);
        }
    }
    #pragma unroll
    for (int o = 32; o >= 1; o >>= 1) lsum += __shfl_xor(lsum, o, 64);
    if (lane == 0) sRed[wv] = lsum;
    __syncthreads();
    if (tid == 0)
        atomicAdd(semLoss, (sRed[0] + sRed[1] + sRed[2] + sRed[3]) * (1.0f / 16777216.f));
}

extern "C" void kernel_launch(void* const* d_in, const int* in_sizes, int n_in,
                              void* d_out, int out_size, void* d_ws, size_t ws_size,
                              hipStream_t stream) {
    const float* z   = (const float*)d_in[0];
    const float* tgt = (const float*)d_in[1];
    const float* E   = (const float*)d_in[2];
    const float* W1  = (const float*)d_in[3];
    const float* b1  = (const float*)d_in[4];
    const float* W2  = (const float*)d_in[5];
    const float* b2  = (const float*)d_in[6];

    float* out   = (float*)d_out;
    float* zq    = out;
    float* codes = out + (size_t)NTOK * DDIM;
    float* vql   = codes + (size_t)NTOK * NCB;       // [vq_loss, semantic_loss]

    char* w = (char*)d_ws;
    float*          res   = (float*)(w);                         // 16 MiB
    unsigned short* resH  = (unsigned short*)(w + 16777216);     // 8 MiB
    unsigned short* resL  = (unsigned short*)(w + 25165824);     // 8 MiB
    unsigned short* Eh    = (unsigned short*)(w + 33554432);     // 10 MiB
    unsigned short* El    = (unsigned short*)(w + 44040192);     // 10 MiB
    unsigned short* zqb   = (unsigned short*)(w + 54525952);     // 8 MiB
    int2*           gSlots= (int2*)(w + 62914560);               // 8 MiB
    int*            gCnt  = (int*)(w + 71303168);                // 1 MiB
    float*          gMin  = (float*)(w + 72351744);              // 1 MiB
    float*          sseE  = (float*)(w + 73400320);              // 80 KiB (pad 128K)
    float*          normA = (float*)(w + 73531392);              // 64 KiB (pad 128K)
    float*          lossPart=(float*)(w + 73662464);             // 160 KiB (pad 256K)
    unsigned short* w1t   = (unsigned short*)(w + 73924608);     // 128 KiB
    unsigned short* w2t   = (unsigned short*)(w + 74055680);     // 512 KiB

    hipMemsetAsync(vql, 0, 2 * sizeof(float), stream);
    norms_all_kernel<<<9216, 256, 0, stream>>>(E, z, sseE, normA);
    conv_all_kernel<<<38144, 256, 0, stream>>>(E, z, W1, W2, Eh, El, resH, resL, w1t, w2t);
    for (int it = 0; it < NCB; ++it) {
        const float*          Ei    = E  + (size_t)it * KCB * DDIM;
        const unsigned short* Ehi   = Eh + (size_t)it * KCB * DDIM;
        const unsigned short* Eli   = El + (size_t)it * KCB * DDIM;
        const float*          sseEi = sseE + (size_t)it * KCB;
        const float* resSrc = (it == 0) ? z : res;
        vq_screen<<<2048, 256, 0, stream>>>(resH, resL, Ehi, Eli, sseEi, gSlots, gCnt, gMin);
        vq_post<<<1024, 256, 0, stream>>>(resSrc, Ei, sseEi, res, zq, codes, lossPart,
                                          normA, resH, resL, zqb, gSlots, gCnt, gMin, it);
        if (it == 0)
            semantic_mfma<<<512, 256, 0, stream>>>(zqb, tgt, w1t, b1, w2t, b2, vql + 1);
    }
    loss_final<<<1, 256, 0, stream>>>(lossPart, vql);
}